// Round 7
// baseline (589.540 us; speedup 1.0000x reference)
//
#include <hip/hip_runtime.h>

// GAT (3x GATConv + MLP head).
// R2: CSR gather. R4: split-f16 MFMA GEMM. R5: f16 messages + fused logits.
// R6: presplit A. R7: 4-stream gather. R9: async DMA staging, buckets.
// R10: hi/lo f16 message tables. R11/R12: aggregate structure (lane-parallel
//      prologue), pinned at 3.9 TB/s random-gather floor (R13) -- FINAL.
// R14: nontemporal experiment REGRESSED. Reverted (R15, 584.9us).
// R16: gemm k-loop pipelining (A dbuf prefetch, B restaged between barriers).
//      568.3us. Gemms now < agg in top-5. Budget: aggs 251us, rest 317us.
// R17: two launch-graph fusions, no numeric change to any accepted kernel:
//      (a) edge-scatter moved from prep into gemm1's grid as trailing blocks
//          (atomic/latency work hides under MFMA; buckets complete before
//          aggregate-1 by kernel-completion ordering).
//      (b) gemm_head fused into the MLP gemm epilogue: h (identical hi/lo
//          split) spilled per-32-row-chunk into dead sA LDS, head MFMA with
//          Wm2 tables from L2, 4 k-quarter partials reduced via LDS
//          atomicAdd. Kills the 102MB Ph/Pl round-trip + one launch.

constexpr int NN = 50000;
constexpr int NE = 800000;
constexpr int NN_PAD = 50176;   // DMA-gather padding for A tables
constexpr int CAP = 48;         // bucket capacity (Poisson(16) max ~40)
constexpr int GEMM_BLKS = (NN + 127) / 128;   // 391
constexpr int SCAT_BLKS = (NE + 511) / 512;   // 1563

typedef _Float16 f16x8 __attribute__((ext_vector_type(8)));
typedef _Float16 f16x4 __attribute__((ext_vector_type(4)));
typedef float    f32x4 __attribute__((ext_vector_type(4)));

// async global->LDS, 16B per lane; LDS dest = wave-uniform base + lane*16
__device__ __forceinline__ void cp16(void* lds, const void* g)
{
    __builtin_amdgcn_global_load_lds(
        (const __attribute__((address_space(1))) uint32_t*)g,
        (__attribute__((address_space(3))) uint32_t*)lds, 16, 0, 0);
}

// ---- weight pre-convert (hi/lo split tables) -------------------------------
constexpr int CVT_BLKS = 944;
__global__ __launch_bounds__(256)
void prep_kernel(const float* __restrict__ W1, const float* __restrict__ W2,
                 const float* __restrict__ W3, const float* __restrict__ Wm1,
                 const float* __restrict__ Wm2,
                 _Float16* B1h, _Float16* B1l, _Float16* B2h, _Float16* B2l,
                 _Float16* B3h, _Float16* B3l, _Float16* Bmh, _Float16* Bml,
                 _Float16* Whh, _Float16* Whl)
{
    int idx = blockIdx.x * 256 + (int)threadIdx.x;
    const float* W; _Float16 *H, *Lo; int K, local;
    if (idx < 32768)       { W = W1;  H = B1h; Lo = B1l; K = 128; local = idx; }
    else if (idx < 98304)  { W = W2;  H = B2h; Lo = B2l; K = 256; local = idx - 32768; }
    else if (idx < 163840) { W = W3;  H = B3h; Lo = B3l; K = 256; local = idx - 98304; }
    else if (idx < 229376) { W = Wm1; H = Bmh; Lo = Bml; K = 256; local = idx - 163840; }
    else if (idx < 241664) {
        int l = idx - 229376; int n = l >> 8, k = l & 255;
        float v = (n < 40) ? Wm2[k * 40 + n] : 0.f;
        _Float16 h = (_Float16)v;
        Whh[l] = h; Whl[l] = (_Float16)(v - (float)h);
        return;
    } else return;
    int k = local >> 8, n = local & 255;     // input layout [K][256]
    float v = W[local];
    _Float16 h = (_Float16)v;
    H[n * K + k] = h;
    Lo[n * K + k] = (_Float16)(v - (float)h);
}

// ---- split-f16 MFMA GEMM: [M,256] = A[M,K] @ B[K,256] ----------------------
// 512 thr (8 waves = 2 Mw x 4 Nw), tile M=128 x N=256, R16 pipeline.
// SCATTER: trailing blocks (>= GEMM_BLKS) do the edge-bucket build.
// HEADF: fused MLP head epilogue (out = relu(C+bias) @ Wm2 + bias2).
template<bool FUSE, bool PRESPLIT, bool HEADF, bool SCATTER>
__global__ __launch_bounds__(512, 4)
void gemm_mfma(const float* __restrict__ A,
               const _Float16* Ah, const _Float16* Al,
               const _Float16* __restrict__ Bhi, const _Float16* __restrict__ Blo,
               const float* __restrict__ bias,
               _Float16* __restrict__ h16, _Float16* __restrict__ h16lo,
               const _Float16* __restrict__ Wh_hi, const _Float16* __restrict__ Wh_lo,
               const float* __restrict__ bias2, float* __restrict__ out,
               const float* __restrict__ a_src, const float* __restrict__ a_dst,
               float* __restrict__ sl, float* __restrict__ dl,
               const int* __restrict__ e_src, const int* __restrict__ e_dst,
               int* __restrict__ cursor, int* __restrict__ bucket,
               int M, int K)
{
    __shared__ __align__(16) _Float16 sAhi[2][128][32], sAlo[2][128][32];  // 16KB each
    __shared__ __align__(16) _Float16 sBhi[256][32], sBlo[256][32];        // 16KB each

    const int tid  = (int)threadIdx.x;

    if (SCATTER && (int)blockIdx.x >= GEMM_BLKS) {
        int e = ((int)blockIdx.x - GEMM_BLKS) * 512 + tid;
        if (e < NE) {
            int d = e_dst[e];
            int pos = atomicAdd(&cursor[d], 1);
            if (pos < CAP) bucket[d * CAP + pos] = e_src[e];
        }
        return;
    }

    const int wave = tid >> 6;
    const int mw   = wave >> 2;         // 0..1
    const int nw   = wave & 3;          // 0..3 == head
    const int lane = tid & 63;
    const int l15  = lane & 15;
    const int quad = lane >> 4;
    const int swz  = (l15 >> 1) & 3;    // read-side swizzle (row-dependent)
    const int bm   = blockIdx.x * 128;

    f32x4 acc[4][4];
    #pragma unroll
    for (int i = 0; i < 4; ++i)
        #pragma unroll
        for (int j = 0; j < 4; ++j)
            acc[i][j] = (f32x4){0.f, 0.f, 0.f, 0.f};

    // ---- staging helpers ----------------------------------------------------
    auto stageA_dma = [&](int b, int k0) {
        int rowA = wave * 16 + (lane >> 2);
        int c = (lane & 3) ^ ((rowA >> 1) & 3);
        cp16(&sAhi[b][wave * 16][0], Ah + (size_t)(bm + rowA) * K + k0 + c * 8);
        cp16(&sAlo[b][wave * 16][0], Al + (size_t)(bm + rowA) * K + k0 + c * 8);
    };
    auto stageB = [&](int k0) {
        int pos = lane & 3;
        #pragma unroll
        for (int j = 0; j < 2; ++j) {
            int rowB = wave * 32 + j * 16 + (lane >> 2);
            int c = pos ^ ((rowB >> 1) & 3);
            cp16(&sBhi[wave * 32 + j * 16][0], Bhi + (size_t)rowB * K + k0 + c * 8);
            cp16(&sBlo[wave * 32 + j * 16][0], Blo + (size_t)rowB * K + k0 + c * 8);
        }
    };
    const int ar = tid >> 2, ac = tid & 3;    // fp32-A path: 4 thr x 8 f16/row
    auto writeA_cvt = [&](int b, float4 v0, float4 v1) {
        float fv[8] = {v0.x, v0.y, v0.z, v0.w, v1.x, v1.y, v1.z, v1.w};
        f16x8 h8, l8;
        #pragma unroll
        for (int u = 0; u < 8; ++u) {
            _Float16 hh = (_Float16)fv[u];
            h8[u] = hh; l8[u] = (_Float16)(fv[u] - (float)hh);
        }
        int slot = (ac ^ ((ar >> 1) & 3)) * 8;
        *(f16x8*)&sAhi[b][ar][slot] = h8;
        *(f16x8*)&sAlo[b][ar][slot] = l8;
    };
    auto loadA32 = [&](int k0, float4& v0, float4& v1) {
        int grow = bm + ar;
        v0 = make_float4(0.f, 0.f, 0.f, 0.f); v1 = v0;
        if (grow < M) {
            v0 = *(const float4*)(A + (size_t)grow * K + k0 + ac * 8);
            v1 = *(const float4*)(A + (size_t)grow * K + k0 + ac * 8 + 4);
        }
    };

    // ---- prologue: stage k=0 into buffer 0 ----------------------------------
    if (PRESPLIT) {
        stageA_dma(0, 0);
    } else {
        float4 v0, v1;
        loadA32(0, v0, v1);
        writeA_cvt(0, v0, v1);
    }
    stageB(0);
    __syncthreads();

    const int NT = K >> 5;
    for (int t = 0; t < NT; ++t) {
        const int cb = t & 1, nb = cb ^ 1;
        const bool pf = (t + 1 < NT);
        const int kn = (t + 1) << 5;

        float4 pv0, pv1;
        if (pf) {
            if (PRESPLIT) stageA_dma(nb, kn);
            else          loadA32(kn, pv0, pv1);
        }

        f16x8 bh[4], bl[4];
        #pragma unroll
        for (int nt = 0; nt < 4; ++nt) {
            int n = nw * 64 + nt * 16 + l15;
            bh[nt] = *(const f16x8*)&sBhi[n][(quad ^ swz) * 8];
            bl[nt] = *(const f16x8*)&sBlo[n][(quad ^ swz) * 8];
        }
        #pragma unroll
        for (int mt = 0; mt < 4; ++mt) {
            int m = mw * 64 + mt * 16 + l15;
            f16x8 ah = *(const f16x8*)&sAhi[cb][m][(quad ^ swz) * 8];
            f16x8 al = *(const f16x8*)&sAlo[cb][m][(quad ^ swz) * 8];
            #pragma unroll
            for (int nt = 0; nt < 4; ++nt) {
                acc[mt][nt] = __builtin_amdgcn_mfma_f32_16x16x32_f16(ah, bh[nt], acc[mt][nt], 0, 0, 0);
                acc[mt][nt] = __builtin_amdgcn_mfma_f32_16x16x32_f16(al, bh[nt], acc[mt][nt], 0, 0, 0);
                acc[mt][nt] = __builtin_amdgcn_mfma_f32_16x16x32_f16(ah, bl[nt], acc[mt][nt], 0, 0, 0);
            }
        }

        if (pf && !PRESPLIT) writeA_cvt(nb, pv0, pv1);

        if (pf) {
            __syncthreads();       // sB readers done; A(t+1) staging drained
            stageB(kn);            // B refill (L2-hot)
            __syncthreads();       // B visible for step t+1
        }
    }

    // ======================= fused MLP head epilogue =========================
    if (HEADF) {
        _Float16* hH = (_Float16*)&sAhi[0][0][0];   // [32][256] chunk of h (hi)
        _Float16* hL = (_Float16*)&sAlo[0][0][0];   // [32][256] chunk of h (lo)
        float* redf  = (float*)&sBhi[0][0];         // red[2][3][16][17] f32
        const int mh = wave & 1, kq = wave >> 1;
        __syncthreads();                            // all k-loop LDS reads done
        for (int mt = 0; mt < 4; ++mt) {
            // spill h = relu(C+bias) hi/lo for this 32-row chunk
            #pragma unroll
            for (int r = 0; r < 4; ++r) {
                int lrow = mw * 16 + quad * 4 + r;
                #pragma unroll
                for (int nt = 0; nt < 4; ++nt) {
                    int col = nw * 64 + nt * 16 + l15;
                    float v = fmaxf(acc[mt][nt][r] + bias[col], 0.f);
                    _Float16 hh = (_Float16)v;
                    hH[lrow * 256 + col] = hh;
                    hL[lrow * 256 + col] = (_Float16)(v - (float)hh);
                }
            }
            for (int z = tid; z < 2 * 3 * 16 * 17; z += 512) redf[z] = 0.f;
            __syncthreads();
            // head MFMA: wave -> (m-tile mh, k-quarter kq)
            f32x4 a3[3];
            #pragma unroll
            for (int nt = 0; nt < 3; ++nt) a3[nt] = (f32x4){0.f, 0.f, 0.f, 0.f};
            #pragma unroll
            for (int kc = 0; kc < 2; ++kc) {
                int k0 = kq * 64 + kc * 32;
                f16x8 ah = *(const f16x8*)&hH[(mh * 16 + l15) * 256 + k0 + quad * 8];
                f16x8 al = *(const f16x8*)&hL[(mh * 16 + l15) * 256 + k0 + quad * 8];
                #pragma unroll
                for (int nt = 0; nt < 3; ++nt) {
                    int n = nt * 16 + l15;
                    f16x8 bh = *(const f16x8*)(Wh_hi + n * 256 + k0 + quad * 8);
                    f16x8 bl = *(const f16x8*)(Wh_lo + n * 256 + k0 + quad * 8);
                    a3[nt] = __builtin_amdgcn_mfma_f32_16x16x32_f16(ah, bh, a3[nt], 0, 0, 0);
                    a3[nt] = __builtin_amdgcn_mfma_f32_16x16x32_f16(al, bh, a3[nt], 0, 0, 0);
                    a3[nt] = __builtin_amdgcn_mfma_f32_16x16x32_f16(ah, bl, a3[nt], 0, 0, 0);
                }
            }
            // reduce 4 k-quarter partials
            #pragma unroll
            for (int nt = 0; nt < 3; ++nt)
                #pragma unroll
                for (int rg = 0; rg < 4; ++rg)
                    atomicAdd(&redf[((mh * 3 + nt) * 16 + l15) * 17 + quad * 4 + rg],
                              a3[nt][rg]);
            __syncthreads();
            if (kq == 0) {
                #pragma unroll
                for (int rg = 0; rg < 4; ++rg) {
                    int grow = bm + mh * 64 + mt * 16 + quad * 4 + rg;
                    if (grow < M) {
                        #pragma unroll
                        for (int nt = 0; nt < 3; ++nt) {
                            int col = nt * 16 + l15;
                            if (col < 40)
                                out[(size_t)grow * 40 + col] =
                                    redf[((mh * 3 + nt) * 16 + l15) * 17 + quad * 4 + rg]
                                    + bias2[col];
                        }
                    }
                }
            }
            __syncthreads();
        }
        return;
    }

    // ======================= normal epilogue =================================
    float aS[4], aD[4];
    if (FUSE) {
        #pragma unroll
        for (int nt = 0; nt < 4; ++nt) {
            aS[nt] = a_src[nw * 64 + nt * 16 + l15];
            aD[nt] = a_dst[nw * 64 + nt * 16 + l15];
        }
    }

    #pragma unroll
    for (int mt = 0; mt < 4; ++mt) {
        #pragma unroll
        for (int r = 0; r < 4; ++r) {
            int row = bm + mw * 64 + mt * 16 + quad * 4 + r;
            bool ok = (row < M);
            if (ok) {
                #pragma unroll
                for (int nt = 0; nt < 4; ++nt) {
                    int col = nw * 64 + nt * 16 + l15;
                    float c = acc[mt][nt][r];
                    _Float16 hh = (_Float16)c;
                    h16[(size_t)row * 256 + col] = hh;
                    h16lo[(size_t)row * 256 + col] = (_Float16)(c - (float)hh);
                }
            }
            if (FUSE) {
                float vs = 0.f, vd = 0.f;
                #pragma unroll
                for (int nt = 0; nt < 4; ++nt) {
                    float c = acc[mt][nt][r];
                    vs = fmaf(c, aS[nt], vs);
                    vd = fmaf(c, aD[nt], vd);
                }
                #pragma unroll
                for (int off = 8; off >= 1; off >>= 1) {
                    vs += __shfl_xor(vs, off, 64);
                    vd += __shfl_xor(vd, off, 64);
                }
                if (l15 == 0 && ok) {
                    sl[row * 4 + nw] = vs;
                    dl[row * 4 + nw] = vd;
                }
            }
        }
    }
}

__device__ __forceinline__ float leaky02(float a) {
    return (a >= 0.f) ? a : 0.2f * a;
}

// ---- fused softmax + aggregation: one wave per destination node ------------
// R12 structure (best measured). Default cache policy.
__global__ __launch_bounds__(256)
void gat_aggregate(const int* __restrict__ cursor, const int* __restrict__ bucket,
                   const float* __restrict__ sl, const float* __restrict__ dl,
                   const _Float16* __restrict__ h16, const _Float16* __restrict__ h16lo,
                   const float* __restrict__ bias,
                   _Float16* __restrict__ Ph, _Float16* __restrict__ Pl)
{
    __shared__ __align__(16) float sE[4][CAP][4];   // [wave][slot][head]
    __shared__ __align__(16) int   sIdx[4][CAP];    // [wave][slot]

    const int wv = (int)threadIdx.x >> 6;
    const int n = blockIdx.x * 4 + wv;
    if (n >= NN) return;
    const int lane = (int)threadIdx.x & 63;
    const int head = lane >> 4;
    const int cnt = min(cursor[n], CAP);

    // ---- pass 1: one neighbor per lane -------------------------------------
    if (lane < cnt) {
        int s = bucket[(size_t)n * CAP + lane];
        sIdx[wv][lane] = s;
        float4 s4 = *(const float4*)(sl + s * 4);
        float4 d4 = *(const float4*)(dl + n * 4);
        float4 e4;
        e4.x = __expf(leaky02(s4.x + d4.x));
        e4.y = __expf(leaky02(s4.y + d4.y));
        e4.z = __expf(leaky02(s4.z + d4.z));
        e4.w = __expf(leaky02(s4.w + d4.w));
        *(float4*)&sE[wv][lane][0] = e4;
    }

    // ---- self-loop (stream 0): exact row = hi + lo -------------------------
    const float dlh = dl[n * 4 + head];
    float exs = __expf(leaky02(sl[n * 4 + head] + dlh));
    f16x4 shi = *(const f16x4*)(h16   + (size_t)n * 256 + lane * 4);
    f16x4 slo = *(const f16x4*)(h16lo + (size_t)n * 256 + lane * 4);
    float4 a0; float d0 = exs;
    a0.x = exs * ((float)shi[0] + (float)slo[0]);
    a0.y = exs * ((float)shi[1] + (float)slo[1]);
    a0.z = exs * ((float)shi[2] + (float)slo[2]);
    a0.w = exs * ((float)shi[3] + (float)slo[3]);
    float4 a1 = {0,0,0,0}, a2 = {0,0,0,0}, a3 = {0,0,0,0};
    float d1 = 0.f, d2 = 0.f, d3 = 0.f;

    const int vo = lane * 4;               // per-lane channel offset (f16 elems)
    int i = 0;
    for (; i + 3 < cnt; i += 4) {
        int s0 = __builtin_amdgcn_readfirstlane(sIdx[wv][i]);
        int s1 = __builtin_amdgcn_readfirstlane(sIdx[wv][i + 1]);
        int s2 = __builtin_amdgcn_readfirstlane(sIdx[wv][i + 2]);
        int s3 = __builtin_amdgcn_readfirstlane(sIdx[wv][i + 3]);
        float e0 = sE[wv][i][head];
        float e1 = sE[wv][i + 1][head];
        float e2 = sE[wv][i + 2][head];
        float e3 = sE[wv][i + 3][head];
        f16x4 h0 = *(const f16x4*)(h16 + ((size_t)(uint32_t)s0 << 8) + vo);
        f16x4 h1 = *(const f16x4*)(h16 + ((size_t)(uint32_t)s1 << 8) + vo);
        f16x4 h2 = *(const f16x4*)(h16 + ((size_t)(uint32_t)s2 << 8) + vo);
        f16x4 h3 = *(const f16x4*)(h16 + ((size_t)(uint32_t)s3 << 8) + vo);
        a0.x = fmaf(e0, (float)h0[0], a0.x); a0.y = fmaf(e0, (float)h0[1], a0.y);
        a0.z = fmaf(e0, (float)h0[2], a0.z); a0.w = fmaf(e0, (float)h0[3], a0.w);
        d0 += e0;
        a1.x = fmaf(e1, (float)h1[0], a1.x); a1.y = fmaf(e1, (float)h1[1], a1.y);
        a1.z = fmaf(e1, (float)h1[2], a1.z); a1.w = fmaf(e1, (float)h1[3], a1.w);
        d1 += e1;
        a2.x = fmaf(e2, (float)h2[0], a2.x); a2.y = fmaf(e2, (float)h2[1], a2.y);
        a2.z = fmaf(e2, (float)h2[2], a2.z); a2.w = fmaf(e2, (float)h2[3], a2.w);
        d2 += e2;
        a3.x = fmaf(e3, (float)h3[0], a3.x); a3.y = fmaf(e3, (float)h3[1], a3.y);
        a3.z = fmaf(e3, (float)h3[2], a3.z); a3.w = fmaf(e3, (float)h3[3], a3.w);
        d3 += e3;
    }
    for (; i < cnt; ++i) {
        int s0 = __builtin_amdgcn_readfirstlane(sIdx[wv][i]);
        float e0 = sE[wv][i][head];
        f16x4 h0 = *(const f16x4*)(h16 + ((size_t)(uint32_t)s0 << 8) + vo);
        a0.x = fmaf(e0, (float)h0[0], a0.x); a0.y = fmaf(e0, (float)h0[1], a0.y);
        a0.z = fmaf(e0, (float)h0[2], a0.z); a0.w = fmaf(e0, (float)h0[3], a0.w);
        d0 += e0;
    }
    float4 acc;
    acc.x = (a0.x + a1.x) + (a2.x + a3.x);
    acc.y = (a0.y + a1.y) + (a2.y + a3.y);
    acc.z = (a0.z + a1.z) + (a2.z + a3.z);
    acc.w = (a0.w + a1.w) + (a2.w + a3.w);
    float denom = (d0 + d1) + (d2 + d3);

    float inv = 1.f / denom;
    float4 bv = *(const float4*)(bias + lane * 4);
    float rv[4];
    rv[0] = fmaxf(bv.x + acc.x * inv, 0.f);
    rv[1] = fmaxf(bv.y + acc.y * inv, 0.f);
    rv[2] = fmaxf(bv.z + acc.z * inv, 0.f);
    rv[3] = fmaxf(bv.w + acc.w * inv, 0.f);
    f16x4 h, l;
    #pragma unroll
    for (int u = 0; u < 4; ++u) {
        _Float16 hh = (_Float16)rv[u];
        h[u] = hh; l[u] = (_Float16)(rv[u] - (float)hh);
    }
    *(f16x4*)(Ph + (size_t)n * 256 + vo) = h;
    *(f16x4*)(Pl + (size_t)n * 256 + vo) = l;
}

extern "C" void kernel_launch(void* const* d_in, const int* in_sizes, int n_in,
                              void* d_out, int out_size, void* d_ws, size_t ws_size,
                              hipStream_t stream)
{
    const float* x   = (const float*)d_in[0];
    const int*   ei  = (const int*)d_in[1];
    const int* src = ei;
    const int* dst = ei + NE;
    const float* W1  = (const float*)d_in[2];
    const float* as1 = (const float*)d_in[3];
    const float* ad1 = (const float*)d_in[4];
    const float* b1  = (const float*)d_in[5];
    const float* W2  = (const float*)d_in[6];
    const float* as2 = (const float*)d_in[7];
    const float* ad2 = (const float*)d_in[8];
    const float* b2  = (const float*)d_in[9];
    const float* W3  = (const float*)d_in[10];
    const float* as3 = (const float*)d_in[11];
    const float* ad3 = (const float*)d_in[12];
    const float* b3  = (const float*)d_in[13];
    const float* Wm1 = (const float*)d_in[14];
    const float* bm1 = (const float*)d_in[15];
    const float* Wm2 = (const float*)d_in[16];
    const float* bm2 = (const float*)d_in[17];
    float* out = (float*)d_out;

    float* ws  = (float*)d_ws;
    float* sl  = ws;                          // [NN,4]
    float* dl  = sl + NN * 4;
    int* cursor = (int*)(dl + NN * 4);        // [NN]
    int* bucket = cursor + NN;                // [NN*CAP]
    uintptr_t fb = (uintptr_t)(bucket + (size_t)NN * CAP);
    fb = (fb + 15) & ~(uintptr_t)15;
    _Float16* wb = (_Float16*)fb;
    _Float16* B1h = wb;                 _Float16* B1l = B1h + 256 * 128;
    _Float16* B2h = B1l + 256 * 128;    _Float16* B2l = B2h + 256 * 256;
    _Float16* B3h = B2l + 256 * 256;    _Float16* B3l = B3h + 256 * 256;
    _Float16* Bmh = B3l + 256 * 256;    _Float16* Bml = Bmh + 256 * 256;
    _Float16* Whh = Bml + 256 * 256;    _Float16* Whl = Whh + 48 * 256;
    _Float16* H16  = Whl + 48 * 256;                    // [NN,256] msg hi
    _Float16* H16l = H16 + (size_t)NN * 256;            // [NN,256] msg lo
    _Float16* Ph  = H16l + (size_t)NN * 256;            // [NN_PAD,256] A hi
    _Float16* Pl  = Ph   + (size_t)NN_PAD * 256;        // [NN_PAD,256] A lo

    const dim3 block(256);
    const dim3 block512(512);
    const dim3 g1Grid(GEMM_BLKS + SCAT_BLKS);   // gemm1 + fused scatter
    const dim3 mfmaGrid(GEMM_BLKS);
    const int aggBlocks = (NN + 3) / 4;       // 1 node per wave, 4 waves

    // ---------------- weight pre-convert ------------------------------------
    (void)hipMemsetAsync(cursor, 0, (size_t)NN * sizeof(int), stream);
    prep_kernel<<<CVT_BLKS, block, 0, stream>>>(
        W1, W2, W3, Wm1, Wm2, B1h, B1l, B2h, B2l, B3h, B3l, Bmh, Bml, Whh, Whl);

    // ---------------- Layer 1 (A = x fp32, K=128) + fused edge scatter ------
    gemm_mfma<true, false, false, true><<<g1Grid, block512, 0, stream>>>(
        x, nullptr, nullptr, B1h, B1l, nullptr, H16, H16l,
        nullptr, nullptr, nullptr, nullptr,
        as1, ad1, sl, dl, src, dst, cursor, bucket, NN, 128);
    gat_aggregate<<<aggBlocks, block, 0, stream>>>(cursor, bucket, sl, dl, H16, H16l, b1, Ph, Pl);

    // ---------------- Layer 2 (A presplit) ----------------------------------
    gemm_mfma<true, true, false, false><<<mfmaGrid, block512, 0, stream>>>(
        nullptr, Ph, Pl, B2h, B2l, nullptr, H16, H16l,
        nullptr, nullptr, nullptr, nullptr,
        as2, ad2, sl, dl, nullptr, nullptr, nullptr, nullptr, NN, 256);
    gat_aggregate<<<aggBlocks, block, 0, stream>>>(cursor, bucket, sl, dl, H16, H16l, b2, Ph, Pl);

    // ---------------- Layer 3 -----------------------------------------------
    gemm_mfma<true, true, false, false><<<mfmaGrid, block512, 0, stream>>>(
        nullptr, Ph, Pl, B3h, B3l, nullptr, H16, H16l,
        nullptr, nullptr, nullptr, nullptr,
        as3, ad3, sl, dl, nullptr, nullptr, nullptr, nullptr, NN, 256);
    gat_aggregate<<<aggBlocks, block, 0, stream>>>(cursor, bucket, sl, dl, H16, H16l, b3, Ph, Pl);

    // ---------------- MLP (Wm1 gemm + fused Wm2 head) ------------------------
    gemm_mfma<false, true, true, false><<<mfmaGrid, block512, 0, stream>>>(
        nullptr, Ph, Pl, Bmh, Bml, bm1, nullptr, nullptr,
        Whh, Whl, bm2, out,
        nullptr, nullptr, nullptr, nullptr, nullptr, nullptr, nullptr, nullptr,
        NN, 256);
}

// Round 8
// 539.557 us; speedup vs baseline: 1.0926x; 1.0926x over previous
//
#include <hip/hip_runtime.h>

// GAT (3x GATConv + MLP head).
// R2: CSR gather. R4: split-f16 MFMA GEMM. R5: f16 messages + fused logits.
// R6: presplit A. R7: 4-stream gather. R9: async DMA staging, buckets.
// R10: hi/lo f16 message tables. R11/R12: aggregate structure (lane-parallel
//      prologue), pinned at 3.9 TB/s random-gather floor (R13) -- FINAL.
// R14: nontemporal REGRESSED. R15: revert (584.9us).
// R16: gemm k-loop pipelining (A dbuf prefetch, B restaged between barriers).
//      568.3us best. R17: scatter-into-gemm1 + fused MLP head. 589.5us --
//      head fusion cost +47us (2.28M LDS bank conflicts on the 512B-stride
//      spill layout + 16 syncthreads + LDS atomics) despite killing 102MB
//      of traffic. REVERTED. Scatter fusion kept (attribution this round).
// R18: R16 structure + scatter as trailing blocks of gemm1's grid only.

constexpr int NN = 50000;
constexpr int NE = 800000;
constexpr int NN_PAD = 50176;   // DMA-gather padding for A tables
constexpr int CAP = 48;         // bucket capacity (Poisson(16) max ~40)
constexpr int GEMM_BLKS = (NN + 127) / 128;   // 391
constexpr int SCAT_BLKS = (NE + 511) / 512;   // 1563

typedef _Float16 f16x8 __attribute__((ext_vector_type(8)));
typedef _Float16 f16x4 __attribute__((ext_vector_type(4)));
typedef float    f32x4 __attribute__((ext_vector_type(4)));

// async global->LDS, 16B per lane; LDS dest = wave-uniform base + lane*16
__device__ __forceinline__ void cp16(void* lds, const void* g)
{
    __builtin_amdgcn_global_load_lds(
        (const __attribute__((address_space(1))) uint32_t*)g,
        (__attribute__((address_space(3))) uint32_t*)lds, 16, 0, 0);
}

// ---- weight pre-convert (hi/lo split tables) -------------------------------
constexpr int CVT_BLKS = 944;
__global__ __launch_bounds__(256)
void prep_kernel(const float* __restrict__ W1, const float* __restrict__ W2,
                 const float* __restrict__ W3, const float* __restrict__ Wm1,
                 const float* __restrict__ Wm2,
                 _Float16* B1h, _Float16* B1l, _Float16* B2h, _Float16* B2l,
                 _Float16* B3h, _Float16* B3l, _Float16* Bmh, _Float16* Bml,
                 _Float16* Whh, _Float16* Whl)
{
    int idx = blockIdx.x * 256 + (int)threadIdx.x;
    const float* W; _Float16 *H, *Lo; int K, local;
    if (idx < 32768)       { W = W1;  H = B1h; Lo = B1l; K = 128; local = idx; }
    else if (idx < 98304)  { W = W2;  H = B2h; Lo = B2l; K = 256; local = idx - 32768; }
    else if (idx < 163840) { W = W3;  H = B3h; Lo = B3l; K = 256; local = idx - 98304; }
    else if (idx < 229376) { W = Wm1; H = Bmh; Lo = Bml; K = 256; local = idx - 163840; }
    else if (idx < 241664) {
        int l = idx - 229376; int n = l >> 8, k = l & 255;
        float v = (n < 40) ? Wm2[k * 40 + n] : 0.f;
        _Float16 h = (_Float16)v;
        Whh[l] = h; Whl[l] = (_Float16)(v - (float)h);
        return;
    } else return;
    int k = local >> 8, n = local & 255;     // input layout [K][256]
    float v = W[local];
    _Float16 h = (_Float16)v;
    H[n * K + k] = h;
    Lo[n * K + k] = (_Float16)(v - (float)h);
}

// ---- split-f16 MFMA GEMM: [M,256] = A[M,K] @ B[K,256] ----------------------
// 512 thr (8 waves = 2 Mw x 4 Nw), tile M=128 x N=256, R16 pipeline
// (A dbuf prefetch, B restaged between barriers).
// SCATTER: trailing blocks (>= GEMM_BLKS) do the edge-bucket build.
// EMIT_SPLIT: emit relu'd hi/lo split of (C+bias) in-place.
template<bool FUSE, bool PRESPLIT, bool EMIT_SPLIT, bool SCATTER>
__global__ __launch_bounds__(512, 4)
void gemm_mfma(const float* __restrict__ A,
               const _Float16* Ah, const _Float16* Al,
               const _Float16* __restrict__ Bhi, const _Float16* __restrict__ Blo,
               const float* __restrict__ bias,
               _Float16* __restrict__ h16, _Float16* __restrict__ h16lo,
               _Float16* Oh, _Float16* Ol,
               const float* __restrict__ a_src, const float* __restrict__ a_dst,
               float* __restrict__ sl, float* __restrict__ dl,
               const int* __restrict__ e_src, const int* __restrict__ e_dst,
               int* __restrict__ cursor, int* __restrict__ bucket,
               int M, int K)
{
    __shared__ __align__(16) _Float16 sAhi[2][128][32], sAlo[2][128][32];  // 32KB
    __shared__ __align__(16) _Float16 sBhi[256][32], sBlo[256][32];        // 32KB

    const int tid  = (int)threadIdx.x;

    if (SCATTER && (int)blockIdx.x >= GEMM_BLKS) {
        int e = ((int)blockIdx.x - GEMM_BLKS) * 512 + tid;
        if (e < NE) {
            int d = e_dst[e];
            int pos = atomicAdd(&cursor[d], 1);
            if (pos < CAP) bucket[d * CAP + pos] = e_src[e];
        }
        return;
    }

    const int wave = tid >> 6;
    const int mw   = wave >> 2;         // 0..1
    const int nw   = wave & 3;          // 0..3 == head
    const int lane = tid & 63;
    const int l15  = lane & 15;
    const int quad = lane >> 4;
    const int swz  = (l15 >> 1) & 3;    // read-side swizzle (row-dependent)
    const int bm   = blockIdx.x * 128;

    f32x4 acc[4][4];
    #pragma unroll
    for (int i = 0; i < 4; ++i)
        #pragma unroll
        for (int j = 0; j < 4; ++j)
            acc[i][j] = (f32x4){0.f, 0.f, 0.f, 0.f};

    // ---- staging helpers ----------------------------------------------------
    auto stageA_dma = [&](int b, int k0) {
        int rowA = wave * 16 + (lane >> 2);
        int c = (lane & 3) ^ ((rowA >> 1) & 3);
        cp16(&sAhi[b][wave * 16][0], Ah + (size_t)(bm + rowA) * K + k0 + c * 8);
        cp16(&sAlo[b][wave * 16][0], Al + (size_t)(bm + rowA) * K + k0 + c * 8);
    };
    auto stageB = [&](int k0) {
        int pos = lane & 3;
        #pragma unroll
        for (int j = 0; j < 2; ++j) {
            int rowB = wave * 32 + j * 16 + (lane >> 2);
            int c = pos ^ ((rowB >> 1) & 3);
            cp16(&sBhi[wave * 32 + j * 16][0], Bhi + (size_t)rowB * K + k0 + c * 8);
            cp16(&sBlo[wave * 32 + j * 16][0], Blo + (size_t)rowB * K + k0 + c * 8);
        }
    };
    const int ar = tid >> 2, ac = tid & 3;    // fp32-A path: 4 thr x 8 f16/row
    auto writeA_cvt = [&](int b, float4 v0, float4 v1) {
        float fv[8] = {v0.x, v0.y, v0.z, v0.w, v1.x, v1.y, v1.z, v1.w};
        f16x8 h8, l8;
        #pragma unroll
        for (int u = 0; u < 8; ++u) {
            _Float16 hh = (_Float16)fv[u];
            h8[u] = hh; l8[u] = (_Float16)(fv[u] - (float)hh);
        }
        int slot = (ac ^ ((ar >> 1) & 3)) * 8;
        *(f16x8*)&sAhi[b][ar][slot] = h8;
        *(f16x8*)&sAlo[b][ar][slot] = l8;
    };
    auto loadA32 = [&](int k0, float4& v0, float4& v1) {
        int grow = bm + ar;
        v0 = make_float4(0.f, 0.f, 0.f, 0.f); v1 = v0;
        if (grow < M) {
            v0 = *(const float4*)(A + (size_t)grow * K + k0 + ac * 8);
            v1 = *(const float4*)(A + (size_t)grow * K + k0 + ac * 8 + 4);
        }
    };

    // ---- prologue: stage k=0 into buffer 0 ----------------------------------
    if (PRESPLIT) {
        stageA_dma(0, 0);
    } else {
        float4 v0, v1;
        loadA32(0, v0, v1);
        writeA_cvt(0, v0, v1);
    }
    stageB(0);
    __syncthreads();

    const int NT = K >> 5;
    for (int t = 0; t < NT; ++t) {
        const int cb = t & 1, nb = cb ^ 1;
        const bool pf = (t + 1 < NT);
        const int kn = (t + 1) << 5;

        float4 pv0, pv1;
        if (pf) {
            if (PRESPLIT) stageA_dma(nb, kn);
            else          loadA32(kn, pv0, pv1);
        }

        f16x8 bh[4], bl[4];
        #pragma unroll
        for (int nt = 0; nt < 4; ++nt) {
            int n = nw * 64 + nt * 16 + l15;
            bh[nt] = *(const f16x8*)&sBhi[n][(quad ^ swz) * 8];
            bl[nt] = *(const f16x8*)&sBlo[n][(quad ^ swz) * 8];
        }
        #pragma unroll
        for (int mt = 0; mt < 4; ++mt) {
            int m = mw * 64 + mt * 16 + l15;
            f16x8 ah = *(const f16x8*)&sAhi[cb][m][(quad ^ swz) * 8];
            f16x8 al = *(const f16x8*)&sAlo[cb][m][(quad ^ swz) * 8];
            #pragma unroll
            for (int nt = 0; nt < 4; ++nt) {
                acc[mt][nt] = __builtin_amdgcn_mfma_f32_16x16x32_f16(ah, bh[nt], acc[mt][nt], 0, 0, 0);
                acc[mt][nt] = __builtin_amdgcn_mfma_f32_16x16x32_f16(al, bh[nt], acc[mt][nt], 0, 0, 0);
                acc[mt][nt] = __builtin_amdgcn_mfma_f32_16x16x32_f16(ah, bl[nt], acc[mt][nt], 0, 0, 0);
            }
        }

        if (pf && !PRESPLIT) writeA_cvt(nb, pv0, pv1);

        if (pf) {
            __syncthreads();       // sB readers done; A(t+1) staging drained
            stageB(kn);            // B refill (L2-hot)
            __syncthreads();       // B visible for step t+1
        }
    }

    float aS[4], aD[4];
    if (FUSE) {
        #pragma unroll
        for (int nt = 0; nt < 4; ++nt) {
            aS[nt] = a_src[nw * 64 + nt * 16 + l15];
            aD[nt] = a_dst[nw * 64 + nt * 16 + l15];
        }
    }

    #pragma unroll
    for (int mt = 0; mt < 4; ++mt) {
        #pragma unroll
        for (int r = 0; r < 4; ++r) {
            int row = bm + mw * 64 + mt * 16 + quad * 4 + r;
            bool ok = (row < M);
            if (ok) {
                #pragma unroll
                for (int nt = 0; nt < 4; ++nt) {
                    int col = nw * 64 + nt * 16 + l15;
                    float c = acc[mt][nt][r];
                    if (EMIT_SPLIT) {
                        float v = fmaxf(c + bias[col], 0.f);
                        _Float16 hh = (_Float16)v;
                        Oh[(size_t)row * 256 + col] = hh;
                        Ol[(size_t)row * 256 + col] = (_Float16)(v - (float)hh);
                    } else {
                        _Float16 hh = (_Float16)c;
                        h16[(size_t)row * 256 + col] = hh;
                        h16lo[(size_t)row * 256 + col] = (_Float16)(c - (float)hh);
                    }
                }
            }
            if (FUSE) {
                float vs = 0.f, vd = 0.f;
                #pragma unroll
                for (int nt = 0; nt < 4; ++nt) {
                    float c = acc[mt][nt][r];
                    vs = fmaf(c, aS[nt], vs);
                    vd = fmaf(c, aD[nt], vd);
                }
                #pragma unroll
                for (int off = 8; off >= 1; off >>= 1) {
                    vs += __shfl_xor(vs, off, 64);
                    vd += __shfl_xor(vd, off, 64);
                }
                if (l15 == 0 && ok) {
                    sl[row * 4 + nw] = vs;
                    dl[row * 4 + nw] = vd;
                }
            }
        }
    }
}

// ---- MFMA head GEMM: out[M,40] = A[M,256] @ Wm2 + bm2 (N padded to 48) -----
__global__ __launch_bounds__(256)
void gemm_head(const _Float16* __restrict__ Ah, const _Float16* __restrict__ Al,
               const _Float16* __restrict__ Bh, const _Float16* __restrict__ Bl,
               const float* __restrict__ bias, float* __restrict__ out, int M)
{
    __shared__ _Float16 sAhi[256][40], sAlo[256][40];
    __shared__ _Float16 sBhi[48][40],  sBlo[48][40];

    const int tid  = (int)threadIdx.x;
    const int wave = tid >> 6;
    const int lane = tid & 63;
    const int l15  = lane & 15;
    const int quad = lane >> 4;
    const int bm   = blockIdx.x * 256;

    f32x4 acc[4][3];
    #pragma unroll
    for (int i = 0; i < 4; ++i)
        #pragma unroll
        for (int j = 0; j < 3; ++j)
            acc[i][j] = (f32x4){0.f, 0.f, 0.f, 0.f};

    for (int k0 = 0; k0 < 256; k0 += 32) {
        #pragma unroll
        for (int i = 0; i < 4; ++i) {
            int idx = tid + i * 256;
            int row = idx >> 2, kq = (idx & 3) * 8;
            int grow = bm + row;
            uint4 vh = {0,0,0,0}, vl = {0,0,0,0};
            if (grow < M) {
                vh = *(const uint4*)(Ah + (size_t)grow * 256 + k0 + kq);
                vl = *(const uint4*)(Al + (size_t)grow * 256 + k0 + kq);
            }
            *(uint4*)&sAhi[row][kq] = vh;
            *(uint4*)&sAlo[row][kq] = vl;
        }
        if (tid < 192) {
            int n = tid >> 2, kq = (tid & 3) * 8;
            *(uint4*)&sBhi[n][kq] = *(const uint4*)(Bh + (size_t)n * 256 + k0 + kq);
            *(uint4*)&sBlo[n][kq] = *(const uint4*)(Bl + (size_t)n * 256 + k0 + kq);
        }
        __syncthreads();

        f16x8 bh[3], bl[3];
        #pragma unroll
        for (int nt = 0; nt < 3; ++nt) {
            int n = nt * 16 + l15;
            bh[nt] = *(const f16x8*)&sBhi[n][quad * 8];
            bl[nt] = *(const f16x8*)&sBlo[n][quad * 8];
        }
        #pragma unroll
        for (int mt = 0; mt < 4; ++mt) {
            int m = wave * 64 + mt * 16 + l15;
            f16x8 ah = *(const f16x8*)&sAhi[m][quad * 8];
            f16x8 al = *(const f16x8*)&sAlo[m][quad * 8];
            #pragma unroll
            for (int nt = 0; nt < 3; ++nt) {
                acc[mt][nt] = __builtin_amdgcn_mfma_f32_16x16x32_f16(ah, bh[nt], acc[mt][nt], 0, 0, 0);
                acc[mt][nt] = __builtin_amdgcn_mfma_f32_16x16x32_f16(al, bh[nt], acc[mt][nt], 0, 0, 0);
                acc[mt][nt] = __builtin_amdgcn_mfma_f32_16x16x32_f16(ah, bl[nt], acc[mt][nt], 0, 0, 0);
            }
        }
        __syncthreads();
    }

    #pragma unroll
    for (int mt = 0; mt < 4; ++mt) {
        #pragma unroll
        for (int r = 0; r < 4; ++r) {
            int row = bm + wave * 64 + mt * 16 + quad * 4 + r;
            if (row >= M) continue;
            #pragma unroll
            for (int nt = 0; nt < 3; ++nt) {
                int col = nt * 16 + l15;
                if (col < 40)
                    out[(size_t)row * 40 + col] = acc[mt][nt][r] + bias[col];
            }
        }
    }
}

__device__ __forceinline__ float leaky02(float a) {
    return (a >= 0.f) ? a : 0.2f * a;
}

// ---- fused softmax + aggregation: one wave per destination node ------------
// R12 structure (best measured). Default cache policy.
__global__ __launch_bounds__(256)
void gat_aggregate(const int* __restrict__ cursor, const int* __restrict__ bucket,
                   const float* __restrict__ sl, const float* __restrict__ dl,
                   const _Float16* __restrict__ h16, const _Float16* __restrict__ h16lo,
                   const float* __restrict__ bias,
                   _Float16* __restrict__ Ph, _Float16* __restrict__ Pl)
{
    __shared__ __align__(16) float sE[4][CAP][4];   // [wave][slot][head]
    __shared__ __align__(16) int   sIdx[4][CAP];    // [wave][slot]

    const int wv = (int)threadIdx.x >> 6;
    const int n = blockIdx.x * 4 + wv;
    if (n >= NN) return;
    const int lane = (int)threadIdx.x & 63;
    const int head = lane >> 4;
    const int cnt = min(cursor[n], CAP);

    // ---- pass 1: one neighbor per lane -------------------------------------
    if (lane < cnt) {
        int s = bucket[(size_t)n * CAP + lane];
        sIdx[wv][lane] = s;
        float4 s4 = *(const float4*)(sl + s * 4);
        float4 d4 = *(const float4*)(dl + n * 4);
        float4 e4;
        e4.x = __expf(leaky02(s4.x + d4.x));
        e4.y = __expf(leaky02(s4.y + d4.y));
        e4.z = __expf(leaky02(s4.z + d4.z));
        e4.w = __expf(leaky02(s4.w + d4.w));
        *(float4*)&sE[wv][lane][0] = e4;
    }

    // ---- self-loop (stream 0): exact row = hi + lo -------------------------
    const float dlh = dl[n * 4 + head];
    float exs = __expf(leaky02(sl[n * 4 + head] + dlh));
    f16x4 shi = *(const f16x4*)(h16   + (size_t)n * 256 + lane * 4);
    f16x4 slo = *(const f16x4*)(h16lo + (size_t)n * 256 + lane * 4);
    float4 a0; float d0 = exs;
    a0.x = exs * ((float)shi[0] + (float)slo[0]);
    a0.y = exs * ((float)shi[1] + (float)slo[1]);
    a0.z = exs * ((float)shi[2] + (float)slo[2]);
    a0.w = exs * ((float)shi[3] + (float)slo[3]);
    float4 a1 = {0,0,0,0}, a2 = {0,0,0,0}, a3 = {0,0,0,0};
    float d1 = 0.f, d2 = 0.f, d3 = 0.f;

    const int vo = lane * 4;               // per-lane channel offset (f16 elems)
    int i = 0;
    for (; i + 3 < cnt; i += 4) {
        int s0 = __builtin_amdgcn_readfirstlane(sIdx[wv][i]);
        int s1 = __builtin_amdgcn_readfirstlane(sIdx[wv][i + 1]);
        int s2 = __builtin_amdgcn_readfirstlane(sIdx[wv][i + 2]);
        int s3 = __builtin_amdgcn_readfirstlane(sIdx[wv][i + 3]);
        float e0 = sE[wv][i][head];
        float e1 = sE[wv][i + 1][head];
        float e2 = sE[wv][i + 2][head];
        float e3 = sE[wv][i + 3][head];
        f16x4 h0 = *(const f16x4*)(h16 + ((size_t)(uint32_t)s0 << 8) + vo);
        f16x4 h1 = *(const f16x4*)(h16 + ((size_t)(uint32_t)s1 << 8) + vo);
        f16x4 h2 = *(const f16x4*)(h16 + ((size_t)(uint32_t)s2 << 8) + vo);
        f16x4 h3 = *(const f16x4*)(h16 + ((size_t)(uint32_t)s3 << 8) + vo);
        a0.x = fmaf(e0, (float)h0[0], a0.x); a0.y = fmaf(e0, (float)h0[1], a0.y);
        a0.z = fmaf(e0, (float)h0[2], a0.z); a0.w = fmaf(e0, (float)h0[3], a0.w);
        d0 += e0;
        a1.x = fmaf(e1, (float)h1[0], a1.x); a1.y = fmaf(e1, (float)h1[1], a1.y);
        a1.z = fmaf(e1, (float)h1[2], a1.z); a1.w = fmaf(e1, (float)h1[3], a1.w);
        d1 += e1;
        a2.x = fmaf(e2, (float)h2[0], a2.x); a2.y = fmaf(e2, (float)h2[1], a2.y);
        a2.z = fmaf(e2, (float)h2[2], a2.z); a2.w = fmaf(e2, (float)h2[3], a2.w);
        d2 += e2;
        a3.x = fmaf(e3, (float)h3[0], a3.x); a3.y = fmaf(e3, (float)h3[1], a3.y);
        a3.z = fmaf(e3, (float)h3[2], a3.z); a3.w = fmaf(e3, (float)h3[3], a3.w);
        d3 += e3;
    }
    for (; i < cnt; ++i) {
        int s0 = __builtin_amdgcn_readfirstlane(sIdx[wv][i]);
        float e0 = sE[wv][i][head];
        f16x4 h0 = *(const f16x4*)(h16 + ((size_t)(uint32_t)s0 << 8) + vo);
        a0.x = fmaf(e0, (float)h0[0], a0.x); a0.y = fmaf(e0, (float)h0[1], a0.y);
        a0.z = fmaf(e0, (float)h0[2], a0.z); a0.w = fmaf(e0, (float)h0[3], a0.w);
        d0 += e0;
    }
    float4 acc;
    acc.x = (a0.x + a1.x) + (a2.x + a3.x);
    acc.y = (a0.y + a1.y) + (a2.y + a3.y);
    acc.z = (a0.z + a1.z) + (a2.z + a3.z);
    acc.w = (a0.w + a1.w) + (a2.w + a3.w);
    float denom = (d0 + d1) + (d2 + d3);

    float inv = 1.f / denom;
    float4 bv = *(const float4*)(bias + lane * 4);
    float rv[4];
    rv[0] = fmaxf(bv.x + acc.x * inv, 0.f);
    rv[1] = fmaxf(bv.y + acc.y * inv, 0.f);
    rv[2] = fmaxf(bv.z + acc.z * inv, 0.f);
    rv[3] = fmaxf(bv.w + acc.w * inv, 0.f);
    f16x4 h, l;
    #pragma unroll
    for (int u = 0; u < 4; ++u) {
        _Float16 hh = (_Float16)rv[u];
        h[u] = hh; l[u] = (_Float16)(rv[u] - (float)hh);
    }
    *(f16x4*)(Ph + (size_t)n * 256 + vo) = h;
    *(f16x4*)(Pl + (size_t)n * 256 + vo) = l;
}

extern "C" void kernel_launch(void* const* d_in, const int* in_sizes, int n_in,
                              void* d_out, int out_size, void* d_ws, size_t ws_size,
                              hipStream_t stream)
{
    const float* x   = (const float*)d_in[0];
    const int*   ei  = (const int*)d_in[1];
    const int* src = ei;
    const int* dst = ei + NE;
    const float* W1  = (const float*)d_in[2];
    const float* as1 = (const float*)d_in[3];
    const float* ad1 = (const float*)d_in[4];
    const float* b1  = (const float*)d_in[5];
    const float* W2  = (const float*)d_in[6];
    const float* as2 = (const float*)d_in[7];
    const float* ad2 = (const float*)d_in[8];
    const float* b2  = (const float*)d_in[9];
    const float* W3  = (const float*)d_in[10];
    const float* as3 = (const float*)d_in[11];
    const float* ad3 = (const float*)d_in[12];
    const float* b3  = (const float*)d_in[13];
    const float* Wm1 = (const float*)d_in[14];
    const float* bm1 = (const float*)d_in[15];
    const float* Wm2 = (const float*)d_in[16];
    const float* bm2 = (const float*)d_in[17];
    float* out = (float*)d_out;

    float* ws  = (float*)d_ws;
    float* sl  = ws;                          // [NN,4]
    float* dl  = sl + NN * 4;
    int* cursor = (int*)(dl + NN * 4);        // [NN]
    int* bucket = cursor + NN;                // [NN*CAP]
    uintptr_t fb = (uintptr_t)(bucket + (size_t)NN * CAP);
    fb = (fb + 15) & ~(uintptr_t)15;
    _Float16* wb = (_Float16*)fb;
    _Float16* B1h = wb;                 _Float16* B1l = B1h + 256 * 128;
    _Float16* B2h = B1l + 256 * 128;    _Float16* B2l = B2h + 256 * 256;
    _Float16* B3h = B2l + 256 * 256;    _Float16* B3l = B3h + 256 * 256;
    _Float16* Bmh = B3l + 256 * 256;    _Float16* Bml = Bmh + 256 * 256;
    _Float16* Whh = Bml + 256 * 256;    _Float16* Whl = Whh + 48 * 256;
    _Float16* H16  = Whl + 48 * 256;                    // [NN,256] msg hi
    _Float16* H16l = H16 + (size_t)NN * 256;            // [NN,256] msg lo
    _Float16* Ph  = H16l + (size_t)NN * 256;            // [NN_PAD,256] A hi
    _Float16* Pl  = Ph   + (size_t)NN_PAD * 256;        // [NN_PAD,256] A lo

    const dim3 block(256);
    const dim3 block512(512);
    const dim3 g1Grid(GEMM_BLKS + SCAT_BLKS);   // gemm1 + fused scatter
    const dim3 mfmaGrid(GEMM_BLKS);
    const dim3 headGrid((NN + 255) / 256);
    const int aggBlocks = (NN + 3) / 4;       // 1 node per wave, 4 waves

    // ---------------- weight pre-convert ------------------------------------
    (void)hipMemsetAsync(cursor, 0, (size_t)NN * sizeof(int), stream);
    prep_kernel<<<CVT_BLKS, block, 0, stream>>>(
        W1, W2, W3, Wm1, Wm2, B1h, B1l, B2h, B2l, B3h, B3l, Bmh, Bml, Whh, Whl);

    // ---------------- Layer 1 (A = x fp32, K=128) + fused edge scatter ------
    gemm_mfma<true, false, false, true><<<g1Grid, block512, 0, stream>>>(
        x, nullptr, nullptr, B1h, B1l, nullptr, H16, H16l, nullptr, nullptr,
        as1, ad1, sl, dl, src, dst, cursor, bucket, NN, 128);
    gat_aggregate<<<aggBlocks, block, 0, stream>>>(cursor, bucket, sl, dl, H16, H16l, b1, Ph, Pl);

    // ---------------- Layer 2 (A presplit) ----------------------------------
    gemm_mfma<true, true, false, false><<<mfmaGrid, block512, 0, stream>>>(
        nullptr, Ph, Pl, B2h, B2l, nullptr, H16, H16l, nullptr, nullptr,
        as2, ad2, sl, dl, nullptr, nullptr, nullptr, nullptr, NN, 256);
    gat_aggregate<<<aggBlocks, block, 0, stream>>>(cursor, bucket, sl, dl, H16, H16l, b2, Ph, Pl);

    // ---------------- Layer 3 -----------------------------------------------
    gemm_mfma<true, true, false, false><<<mfmaGrid, block512, 0, stream>>>(
        nullptr, Ph, Pl, B3h, B3l, nullptr, H16, H16l, nullptr, nullptr,
        as3, ad3, sl, dl, nullptr, nullptr, nullptr, nullptr, NN, 256);
    gat_aggregate<<<aggBlocks, block, 0, stream>>>(cursor, bucket, sl, dl, H16, H16l, b3, Ph, Pl);

    // ---------------- MLP head ----------------------------------------------
    gemm_mfma<false, true, true, false><<<mfmaGrid, block512, 0, stream>>>(
        nullptr, Ph, Pl, Bmh, Bml, bm1, nullptr, nullptr, Ph, Pl,
        nullptr, nullptr, nullptr, nullptr, nullptr, nullptr, nullptr, nullptr,
        NN, 256);
    gemm_head<<<headGrid, block, 0, stream>>>(Ph, Pl, Whh, Whl, bm2, out, NN);
}

// Round 9
// 532.635 us; speedup vs baseline: 1.1068x; 1.0130x over previous
//
#include <hip/hip_runtime.h>

// GAT (3x GATConv + MLP head).
// R2: CSR gather. R4: split-f16 MFMA GEMM. R5: f16 messages + fused logits.
// R6: presplit A. R7: 4-stream gather. R9: async DMA staging, buckets.
// R10: hi/lo f16 message tables. R11/R12: aggregate structure, pinned at
//      3.9 TB/s random-gather floor (R13) -- FINAL.
// R14: nontemporal REGRESSED (revert R15). R16: gemm k-loop pipelining
//      (A dbuf prefetch) 568.3. R17: head fusion +scatter: 589.5 -- head
//      epilogue cost 2.28M LDS bank conflicts ([32][256] spill = 512B
//      stride) + LDS atomics. R18: scatter-only fusion: 539.6 (WIN -29).
// R19: (a) head fusion RETRY, conflict-free: spill stride 264 f16
//      (132 dw === 4 mod 32 -> uniform 8 dw/bank on b128 reads, min);
//      per-kq redf partial slots (plain stores + 4-sum, no atomics).
//      Keeps R17's proven 102MB traffic kill without the exec penalty.
//      (b) prep shrunk to B1-only; W2/W3/Wm1/Wm2 conversion moved into
//      gemm1's trailing blocks (R18's proven hiding mechanism).

constexpr int NN = 50000;
constexpr int NE = 800000;
constexpr int NN_PAD = 50176;   // DMA-gather padding for A tables
constexpr int CAP = 48;         // bucket capacity (Poisson(16) max ~40)
constexpr int GEMM_BLKS = (NN + 127) / 128;   // 391
constexpr int SCAT_BLKS = (NE + 511) / 512;   // 1563
constexpr int CONV_ELEMS = 241664 - 32768;    // W2..Wm2 conversions
constexpr int CONV_BLKS = CONV_ELEMS / 512;   // 408 (exact)

typedef _Float16 f16x8 __attribute__((ext_vector_type(8)));
typedef _Float16 f16x4 __attribute__((ext_vector_type(4)));
typedef float    f32x4 __attribute__((ext_vector_type(4)));

// async global->LDS, 16B per lane; LDS dest = wave-uniform base + lane*16
__device__ __forceinline__ void cp16(void* lds, const void* g)
{
    __builtin_amdgcn_global_load_lds(
        (const __attribute__((address_space(1))) uint32_t*)g,
        (__attribute__((address_space(3))) uint32_t*)lds, 16, 0, 0);
}

// ---- weight pre-convert: B1 only (gemm1's dependency) ----------------------
__global__ __launch_bounds__(256)
void prep_kernel(const float* __restrict__ W1, _Float16* B1h, _Float16* B1l)
{
    int idx = blockIdx.x * 256 + (int)threadIdx.x;   // < 32768
    int k = idx >> 8, n = idx & 255;                 // input layout [K=128][256]
    float v = W1[idx];
    _Float16 h = (_Float16)v;
    B1h[n * 128 + k] = h;
    B1l[n * 128 + k] = (_Float16)(v - (float)h);
}

// ---- split-f16 MFMA GEMM: [M,256] = A[M,K] @ B[K,256] ----------------------
// 512 thr (8 waves = 2 Mw x 4 Nw), tile M=128 x N=256, R16 pipeline.
// EXTRA: trailing blocks do edge-bucket scatter then W2..Wm2 conversion.
// HEADF: fused MLP head epilogue (out = relu(C+bias) @ Wm2 + bias2).
template<bool FUSE, bool PRESPLIT, bool HEADF, bool EXTRA>
__global__ __launch_bounds__(512, 4)
void gemm_mfma(const float* __restrict__ A,
               const _Float16* Ah, const _Float16* Al,
               const _Float16* __restrict__ Bhi, const _Float16* __restrict__ Blo,
               const float* __restrict__ bias,
               _Float16* __restrict__ h16, _Float16* __restrict__ h16lo,
               const _Float16* __restrict__ Wh_hi, const _Float16* __restrict__ Wh_lo,
               const float* __restrict__ bias2, float* __restrict__ out,
               const float* __restrict__ a_src, const float* __restrict__ a_dst,
               float* __restrict__ sl, float* __restrict__ dl,
               const int* __restrict__ e_src, const int* __restrict__ e_dst,
               int* __restrict__ cursor, int* __restrict__ bucket,
               const float* __restrict__ W2c, const float* __restrict__ W3c,
               const float* __restrict__ Wm1c, const float* __restrict__ Wm2c,
               _Float16* B2hc, _Float16* B2lc, _Float16* B3hc, _Float16* B3lc,
               _Float16* Bmhc, _Float16* Bmlc, _Float16* Whhc, _Float16* Whlc,
               int M, int K)
{
    // 64 KB flat LDS: main loop uses sA dbuf (16KB x2) + sB (8KB x2 x2);
    // HEADF epilogue re-carves: hH[32][264] | hL[32][264] | redf[4][1632]f32.
    __shared__ __align__(16) _Float16 smem[32768];
    _Float16* sAhiP = smem;             // [2][128][32]: b*4096 + r*32
    _Float16* sAloP = smem + 8192;
    _Float16* sBhiP = smem + 16384;     // [256][32]: n*32
    _Float16* sBloP = smem + 24576;

    const int tid  = (int)threadIdx.x;

    if (EXTRA && (int)blockIdx.x >= GEMM_BLKS) {
        int xb = (int)blockIdx.x - GEMM_BLKS;
        if (xb < SCAT_BLKS) {
            int e = xb * 512 + tid;
            if (e < NE) {
                int d = e_dst[e];
                int pos = atomicAdd(&cursor[d], 1);
                if (pos < CAP) bucket[d * CAP + pos] = e_src[e];
            }
        } else {
            int cidx = (xb - SCAT_BLKS) * 512 + tid + 32768;
            const float* W; _Float16 *H, *Lo; int local;
            if (cidx < 98304)       { W = W2c;  H = B2hc; Lo = B2lc; local = cidx - 32768; }
            else if (cidx < 163840) { W = W3c;  H = B3hc; Lo = B3lc; local = cidx - 98304; }
            else if (cidx < 229376) { W = Wm1c; H = Bmhc; Lo = Bmlc; local = cidx - 163840; }
            else {
                int l = cidx - 229376; int n = l >> 8, k = l & 255;
                float v = (n < 40) ? Wm2c[k * 40 + n] : 0.f;
                _Float16 h = (_Float16)v;
                Whhc[l] = h; Whlc[l] = (_Float16)(v - (float)h);
                return;
            }
            int k = local >> 8, n = local & 255;     // [K=256][256] input
            float v = W[local];
            _Float16 h = (_Float16)v;
            H[n * 256 + k] = h;
            Lo[n * 256 + k] = (_Float16)(v - (float)h);
        }
        return;
    }

    const int wave = tid >> 6;
    const int mw   = wave >> 2;         // 0..1
    const int nw   = wave & 3;          // 0..3 == head
    const int lane = tid & 63;
    const int l15  = lane & 15;
    const int quad = lane >> 4;
    const int swz  = (l15 >> 1) & 3;    // read-side swizzle (row-dependent)
    const int bm   = blockIdx.x * 128;

    f32x4 acc[4][4];
    #pragma unroll
    for (int i = 0; i < 4; ++i)
        #pragma unroll
        for (int j = 0; j < 4; ++j)
            acc[i][j] = (f32x4){0.f, 0.f, 0.f, 0.f};

    // ---- staging helpers ----------------------------------------------------
    auto stageA_dma = [&](int b, int k0) {
        int rowA = wave * 16 + (lane >> 2);
        int c = (lane & 3) ^ ((rowA >> 1) & 3);
        cp16(sAhiP + b * 4096 + wave * 512, Ah + (size_t)(bm + rowA) * K + k0 + c * 8);
        cp16(sAloP + b * 4096 + wave * 512, Al + (size_t)(bm + rowA) * K + k0 + c * 8);
    };
    auto stageB = [&](int k0) {
        int pos = lane & 3;
        #pragma unroll
        for (int j = 0; j < 2; ++j) {
            int rowB = wave * 32 + j * 16 + (lane >> 2);
            int c = pos ^ ((rowB >> 1) & 3);
            cp16(sBhiP + (wave * 32 + j * 16) * 32, Bhi + (size_t)rowB * K + k0 + c * 8);
            cp16(sBloP + (wave * 32 + j * 16) * 32, Blo + (size_t)rowB * K + k0 + c * 8);
        }
    };
    const int ar = tid >> 2, ac = tid & 3;    // fp32-A path: 4 thr x 8 f16/row
    auto writeA_cvt = [&](int b, float4 v0, float4 v1) {
        float fv[8] = {v0.x, v0.y, v0.z, v0.w, v1.x, v1.y, v1.z, v1.w};
        f16x8 h8, l8;
        #pragma unroll
        for (int u = 0; u < 8; ++u) {
            _Float16 hh = (_Float16)fv[u];
            h8[u] = hh; l8[u] = (_Float16)(fv[u] - (float)hh);
        }
        int slot = (ac ^ ((ar >> 1) & 3)) * 8;
        *(f16x8*)(sAhiP + b * 4096 + ar * 32 + slot) = h8;
        *(f16x8*)(sAloP + b * 4096 + ar * 32 + slot) = l8;
    };
    auto loadA32 = [&](int k0, float4& v0, float4& v1) {
        int grow = bm + ar;
        v0 = make_float4(0.f, 0.f, 0.f, 0.f); v1 = v0;
        if (grow < M) {
            v0 = *(const float4*)(A + (size_t)grow * K + k0 + ac * 8);
            v1 = *(const float4*)(A + (size_t)grow * K + k0 + ac * 8 + 4);
        }
    };

    // ---- prologue: stage k=0 into buffer 0 ----------------------------------
    if (PRESPLIT) {
        stageA_dma(0, 0);
    } else {
        float4 v0, v1;
        loadA32(0, v0, v1);
        writeA_cvt(0, v0, v1);
    }
    stageB(0);
    __syncthreads();

    const int NT = K >> 5;
    for (int t = 0; t < NT; ++t) {
        const int cb = t & 1, nb = cb ^ 1;
        const bool pf = (t + 1 < NT);
        const int kn = (t + 1) << 5;

        float4 pv0, pv1;
        if (pf) {
            if (PRESPLIT) stageA_dma(nb, kn);
            else          loadA32(kn, pv0, pv1);
        }

        f16x8 bh[4], bl[4];
        #pragma unroll
        for (int nt = 0; nt < 4; ++nt) {
            int n = nw * 64 + nt * 16 + l15;
            bh[nt] = *(const f16x8*)(sBhiP + n * 32 + (quad ^ swz) * 8);
            bl[nt] = *(const f16x8*)(sBloP + n * 32 + (quad ^ swz) * 8);
        }
        #pragma unroll
        for (int mt = 0; mt < 4; ++mt) {
            int m = mw * 64 + mt * 16 + l15;
            f16x8 ah = *(const f16x8*)(sAhiP + cb * 4096 + m * 32 + (quad ^ swz) * 8);
            f16x8 al = *(const f16x8*)(sAloP + cb * 4096 + m * 32 + (quad ^ swz) * 8);
            #pragma unroll
            for (int nt = 0; nt < 4; ++nt) {
                acc[mt][nt] = __builtin_amdgcn_mfma_f32_16x16x32_f16(ah, bh[nt], acc[mt][nt], 0, 0, 0);
                acc[mt][nt] = __builtin_amdgcn_mfma_f32_16x16x32_f16(al, bh[nt], acc[mt][nt], 0, 0, 0);
                acc[mt][nt] = __builtin_amdgcn_mfma_f32_16x16x32_f16(ah, bl[nt], acc[mt][nt], 0, 0, 0);
            }
        }

        if (pf && !PRESPLIT) writeA_cvt(nb, pv0, pv1);

        if (pf) {
            __syncthreads();       // sB readers done; A(t+1) staging drained
            stageB(kn);            // B refill (L2-hot)
            __syncthreads();       // B visible for step t+1
        }
    }

    // ======================= fused MLP head epilogue =========================
    if (HEADF) {
        // re-carve LDS: hH/hL [32][264] (stride 264 f16 = 132 dw === 4 mod 32
        // -> b128 reads land uniform 8 dw/bank = minimum; spill writes ~2-way)
        _Float16* hH  = smem;                       // 8448 f16
        _Float16* hL  = smem + 8448;                // 8448 f16
        float*    redf = (float*)(smem + 16896);    // [4][1632] f32 (26KB)
        const int mh = wave & 1, kq = wave >> 1;
        __syncthreads();                            // all k-loop LDS reads done
        for (int mt = 0; mt < 4; ++mt) {
            // spill h = relu(C+bias) hi/lo for this chunk (rows mh*16+q*4+r)
            #pragma unroll
            for (int r = 0; r < 4; ++r) {
                int lrow = mw * 16 + quad * 4 + r;
                #pragma unroll
                for (int nt = 0; nt < 4; ++nt) {
                    int col = nw * 64 + nt * 16 + l15;
                    float v = fmaxf(acc[mt][nt][r] + bias[col], 0.f);
                    _Float16 hh = (_Float16)v;
                    hH[lrow * 264 + col] = hh;
                    hL[lrow * 264 + col] = (_Float16)(v - (float)hh);
                }
            }
            __syncthreads();
            // head MFMA: wave -> (m-half mh, k-quarter kq)
            f32x4 a3[3];
            #pragma unroll
            for (int nt = 0; nt < 3; ++nt) a3[nt] = (f32x4){0.f, 0.f, 0.f, 0.f};
            #pragma unroll
            for (int kc = 0; kc < 2; ++kc) {
                int k0 = kq * 64 + kc * 32;
                f16x8 ah = *(const f16x8*)&hH[(mh * 16 + l15) * 264 + k0 + quad * 8];
                f16x8 al = *(const f16x8*)&hL[(mh * 16 + l15) * 264 + k0 + quad * 8];
                #pragma unroll
                for (int nt = 0; nt < 3; ++nt) {
                    int n = nt * 16 + l15;
                    f16x8 bh = *(const f16x8*)(Wh_hi + n * 256 + k0 + quad * 8);
                    f16x8 bl = *(const f16x8*)(Wh_lo + n * 256 + k0 + quad * 8);
                    a3[nt] = __builtin_amdgcn_mfma_f32_16x16x32_f16(ah, bh, a3[nt], 0, 0, 0);
                    a3[nt] = __builtin_amdgcn_mfma_f32_16x16x32_f16(al, bh, a3[nt], 0, 0, 0);
                    a3[nt] = __builtin_amdgcn_mfma_f32_16x16x32_f16(ah, bl, a3[nt], 0, 0, 0);
                }
            }
            // store k-quarter partials (plain stores, per-kq slots)
            #pragma unroll
            for (int nt = 0; nt < 3; ++nt)
                #pragma unroll
                for (int rg = 0; rg < 4; ++rg)
                    redf[kq * 1632 + ((mh * 3 + nt) * 16 + l15) * 17 + quad * 4 + rg]
                        = a3[nt][rg];
            __syncthreads();
            if (kq == 0) {     // waves 0 (mh=0), 1 (mh=1) write the output
                #pragma unroll
                for (int rg = 0; rg < 4; ++rg) {
                    int grow = bm + mh * 64 + mt * 16 + quad * 4 + rg;
                    if (grow < M) {
                        #pragma unroll
                        for (int nt = 0; nt < 3; ++nt) {
                            int col = nt * 16 + l15;
                            if (col < 40) {
                                int ix = ((mh * 3 + nt) * 16 + l15) * 17 + quad * 4 + rg;
                                float s = ((redf[ix] + redf[1632 + ix])
                                         + redf[2 * 1632 + ix]) + redf[3 * 1632 + ix];
                                out[(size_t)grow * 40 + col] = s + bias2[col];
                            }
                        }
                    }
                }
            }
            __syncthreads();   // hH reuse next mt
        }
        return;
    }

    // ======================= normal epilogue =================================
    float aS[4], aD[4];
    if (FUSE) {
        #pragma unroll
        for (int nt = 0; nt < 4; ++nt) {
            aS[nt] = a_src[nw * 64 + nt * 16 + l15];
            aD[nt] = a_dst[nw * 64 + nt * 16 + l15];
        }
    }

    #pragma unroll
    for (int mt = 0; mt < 4; ++mt) {
        #pragma unroll
        for (int r = 0; r < 4; ++r) {
            int row = bm + mw * 64 + mt * 16 + quad * 4 + r;
            bool ok = (row < M);
            if (ok) {
                #pragma unroll
                for (int nt = 0; nt < 4; ++nt) {
                    int col = nw * 64 + nt * 16 + l15;
                    float c = acc[mt][nt][r];
                    _Float16 hh = (_Float16)c;
                    h16[(size_t)row * 256 + col] = hh;
                    h16lo[(size_t)row * 256 + col] = (_Float16)(c - (float)hh);
                }
            }
            if (FUSE) {
                float vs = 0.f, vd = 0.f;
                #pragma unroll
                for (int nt = 0; nt < 4; ++nt) {
                    float c = acc[mt][nt][r];
                    vs = fmaf(c, aS[nt], vs);
                    vd = fmaf(c, aD[nt], vd);
                }
                #pragma unroll
                for (int off = 8; off >= 1; off >>= 1) {
                    vs += __shfl_xor(vs, off, 64);
                    vd += __shfl_xor(vd, off, 64);
                }
                if (l15 == 0 && ok) {
                    sl[row * 4 + nw] = vs;
                    dl[row * 4 + nw] = vd;
                }
            }
        }
    }
}

__device__ __forceinline__ float leaky02(float a) {
    return (a >= 0.f) ? a : 0.2f * a;
}

// ---- fused softmax + aggregation: one wave per destination node ------------
// R12 structure (best measured). Default cache policy.
__global__ __launch_bounds__(256)
void gat_aggregate(const int* __restrict__ cursor, const int* __restrict__ bucket,
                   const float* __restrict__ sl, const float* __restrict__ dl,
                   const _Float16* __restrict__ h16, const _Float16* __restrict__ h16lo,
                   const float* __restrict__ bias,
                   _Float16* __restrict__ Ph, _Float16* __restrict__ Pl)
{
    __shared__ __align__(16) float sE[4][CAP][4];   // [wave][slot][head]
    __shared__ __align__(16) int   sIdx[4][CAP];    // [wave][slot]

    const int wv = (int)threadIdx.x >> 6;
    const int n = blockIdx.x * 4 + wv;
    if (n >= NN) return;
    const int lane = (int)threadIdx.x & 63;
    const int head = lane >> 4;
    const int cnt = min(cursor[n], CAP);

    // ---- pass 1: one neighbor per lane -------------------------------------
    if (lane < cnt) {
        int s = bucket[(size_t)n * CAP + lane];
        sIdx[wv][lane] = s;
        float4 s4 = *(const float4*)(sl + s * 4);
        float4 d4 = *(const float4*)(dl + n * 4);
        float4 e4;
        e4.x = __expf(leaky02(s4.x + d4.x));
        e4.y = __expf(leaky02(s4.y + d4.y));
        e4.z = __expf(leaky02(s4.z + d4.z));
        e4.w = __expf(leaky02(s4.w + d4.w));
        *(float4*)&sE[wv][lane][0] = e4;
    }

    // ---- self-loop (stream 0): exact row = hi + lo -------------------------
    const float dlh = dl[n * 4 + head];
    float exs = __expf(leaky02(sl[n * 4 + head] + dlh));
    f16x4 shi = *(const f16x4*)(h16   + (size_t)n * 256 + lane * 4);
    f16x4 slo = *(const f16x4*)(h16lo + (size_t)n * 256 + lane * 4);
    float4 a0; float d0 = exs;
    a0.x = exs * ((float)shi[0] + (float)slo[0]);
    a0.y = exs * ((float)shi[1] + (float)slo[1]);
    a0.z = exs * ((float)shi[2] + (float)slo[2]);
    a0.w = exs * ((float)shi[3] + (float)slo[3]);
    float4 a1 = {0,0,0,0}, a2 = {0,0,0,0}, a3 = {0,0,0,0};
    float d1 = 0.f, d2 = 0.f, d3 = 0.f;

    const int vo = lane * 4;               // per-lane channel offset (f16 elems)
    int i = 0;
    for (; i + 3 < cnt; i += 4) {
        int s0 = __builtin_amdgcn_readfirstlane(sIdx[wv][i]);
        int s1 = __builtin_amdgcn_readfirstlane(sIdx[wv][i + 1]);
        int s2 = __builtin_amdgcn_readfirstlane(sIdx[wv][i + 2]);
        int s3 = __builtin_amdgcn_readfirstlane(sIdx[wv][i + 3]);
        float e0 = sE[wv][i][head];
        float e1 = sE[wv][i + 1][head];
        float e2 = sE[wv][i + 2][head];
        float e3 = sE[wv][i + 3][head];
        f16x4 h0 = *(const f16x4*)(h16 + ((size_t)(uint32_t)s0 << 8) + vo);
        f16x4 h1 = *(const f16x4*)(h16 + ((size_t)(uint32_t)s1 << 8) + vo);
        f16x4 h2 = *(const f16x4*)(h16 + ((size_t)(uint32_t)s2 << 8) + vo);
        f16x4 h3 = *(const f16x4*)(h16 + ((size_t)(uint32_t)s3 << 8) + vo);
        a0.x = fmaf(e0, (float)h0[0], a0.x); a0.y = fmaf(e0, (float)h0[1], a0.y);
        a0.z = fmaf(e0, (float)h0[2], a0.z); a0.w = fmaf(e0, (float)h0[3], a0.w);
        d0 += e0;
        a1.x = fmaf(e1, (float)h1[0], a1.x); a1.y = fmaf(e1, (float)h1[1], a1.y);
        a1.z = fmaf(e1, (float)h1[2], a1.z); a1.w = fmaf(e1, (float)h1[3], a1.w);
        d1 += e1;
        a2.x = fmaf(e2, (float)h2[0], a2.x); a2.y = fmaf(e2, (float)h2[1], a2.y);
        a2.z = fmaf(e2, (float)h2[2], a2.z); a2.w = fmaf(e2, (float)h2[3], a2.w);
        d2 += e2;
        a3.x = fmaf(e3, (float)h3[0], a3.x); a3.y = fmaf(e3, (float)h3[1], a3.y);
        a3.z = fmaf(e3, (float)h3[2], a3.z); a3.w = fmaf(e3, (float)h3[3], a3.w);
        d3 += e3;
    }
    for (; i < cnt; ++i) {
        int s0 = __builtin_amdgcn_readfirstlane(sIdx[wv][i]);
        float e0 = sE[wv][i][head];
        f16x4 h0 = *(const f16x4*)(h16 + ((size_t)(uint32_t)s0 << 8) + vo);
        a0.x = fmaf(e0, (float)h0[0], a0.x); a0.y = fmaf(e0, (float)h0[1], a0.y);
        a0.z = fmaf(e0, (float)h0[2], a0.z); a0.w = fmaf(e0, (float)h0[3], a0.w);
        d0 += e0;
    }
    float4 acc;
    acc.x = (a0.x + a1.x) + (a2.x + a3.x);
    acc.y = (a0.y + a1.y) + (a2.y + a3.y);
    acc.z = (a0.z + a1.z) + (a2.z + a3.z);
    acc.w = (a0.w + a1.w) + (a2.w + a3.w);
    float denom = (d0 + d1) + (d2 + d3);

    float inv = 1.f / denom;
    float4 bv = *(const float4*)(bias + lane * 4);
    float rv[4];
    rv[0] = fmaxf(bv.x + acc.x * inv, 0.f);
    rv[1] = fmaxf(bv.y + acc.y * inv, 0.f);
    rv[2] = fmaxf(bv.z + acc.z * inv, 0.f);
    rv[3] = fmaxf(bv.w + acc.w * inv, 0.f);
    f16x4 h, l;
    #pragma unroll
    for (int u = 0; u < 4; ++u) {
        _Float16 hh = (_Float16)rv[u];
        h[u] = hh; l[u] = (_Float16)(rv[u] - (float)hh);
    }
    *(f16x4*)(Ph + (size_t)n * 256 + vo) = h;
    *(f16x4*)(Pl + (size_t)n * 256 + vo) = l;
}

extern "C" void kernel_launch(void* const* d_in, const int* in_sizes, int n_in,
                              void* d_out, int out_size, void* d_ws, size_t ws_size,
                              hipStream_t stream)
{
    const float* x   = (const float*)d_in[0];
    const int*   ei  = (const int*)d_in[1];
    const int* src = ei;
    const int* dst = ei + NE;
    const float* W1  = (const float*)d_in[2];
    const float* as1 = (const float*)d_in[3];
    const float* ad1 = (const float*)d_in[4];
    const float* b1  = (const float*)d_in[5];
    const float* W2  = (const float*)d_in[6];
    const float* as2 = (const float*)d_in[7];
    const float* ad2 = (const float*)d_in[8];
    const float* b2  = (const float*)d_in[9];
    const float* W3  = (const float*)d_in[10];
    const float* as3 = (const float*)d_in[11];
    const float* ad3 = (const float*)d_in[12];
    const float* b3  = (const float*)d_in[13];
    const float* Wm1 = (const float*)d_in[14];
    const float* bm1 = (const float*)d_in[15];
    const float* Wm2 = (const float*)d_in[16];
    const float* bm2 = (const float*)d_in[17];
    float* out = (float*)d_out;

    float* ws  = (float*)d_ws;
    float* sl  = ws;                          // [NN,4]
    float* dl  = sl + NN * 4;
    int* cursor = (int*)(dl + NN * 4);        // [NN]
    int* bucket = cursor + NN;                // [NN*CAP]
    uintptr_t fb = (uintptr_t)(bucket + (size_t)NN * CAP);
    fb = (fb + 15) & ~(uintptr_t)15;
    _Float16* wb = (_Float16*)fb;
    _Float16* B1h = wb;                 _Float16* B1l = B1h + 256 * 128;
    _Float16* B2h = B1l + 256 * 128;    _Float16* B2l = B2h + 256 * 256;
    _Float16* B3h = B2l + 256 * 256;    _Float16* B3l = B3h + 256 * 256;
    _Float16* Bmh = B3l + 256 * 256;    _Float16* Bml = Bmh + 256 * 256;
    _Float16* Whh = Bml + 256 * 256;    _Float16* Whl = Whh + 48 * 256;
    _Float16* H16  = Whl + 48 * 256;                    // [NN,256] msg hi
    _Float16* H16l = H16 + (size_t)NN * 256;            // [NN,256] msg lo
    _Float16* Ph  = H16l + (size_t)NN * 256;            // [NN_PAD,256] A hi
    _Float16* Pl  = Ph   + (size_t)NN_PAD * 256;        // [NN_PAD,256] A lo

    const dim3 block(256);
    const dim3 block512(512);
    const dim3 g1Grid(GEMM_BLKS + SCAT_BLKS + CONV_BLKS); // gemm1+scatter+conv
    const dim3 mfmaGrid(GEMM_BLKS);
    const int aggBlocks = (NN + 3) / 4;       // 1 node per wave, 4 waves

    // ---------------- B1 pre-convert (gemm1's only dependency) --------------
    (void)hipMemsetAsync(cursor, 0, (size_t)NN * sizeof(int), stream);
    prep_kernel<<<128, block, 0, stream>>>(W1, B1h, B1l);

    // ------ Layer 1 (A = x fp32, K=128) + fused scatter + W2..Wm2 conv ------
    gemm_mfma<true, false, false, true><<<g1Grid, block512, 0, stream>>>(
        x, nullptr, nullptr, B1h, B1l, nullptr, H16, H16l,
        nullptr, nullptr, nullptr, nullptr,
        as1, ad1, sl, dl, src, dst, cursor, bucket,
        W2, W3, Wm1, Wm2, B2h, B2l, B3h, B3l, Bmh, Bml, Whh, Whl, NN, 128);
    gat_aggregate<<<aggBlocks, block, 0, stream>>>(cursor, bucket, sl, dl, H16, H16l, b1, Ph, Pl);

    // ---------------- Layer 2 (A presplit) ----------------------------------
    gemm_mfma<true, true, false, false><<<mfmaGrid, block512, 0, stream>>>(
        nullptr, Ph, Pl, B2h, B2l, nullptr, H16, H16l,
        nullptr, nullptr, nullptr, nullptr,
        as2, ad2, sl, dl, nullptr, nullptr, nullptr, nullptr,
        nullptr, nullptr, nullptr, nullptr,
        nullptr, nullptr, nullptr, nullptr, nullptr, nullptr, nullptr, nullptr,
        NN, 256);
    gat_aggregate<<<aggBlocks, block, 0, stream>>>(cursor, bucket, sl, dl, H16, H16l, b2, Ph, Pl);

    // ---------------- Layer 3 -----------------------------------------------
    gemm_mfma<true, true, false, false><<<mfmaGrid, block512, 0, stream>>>(
        nullptr, Ph, Pl, B3h, B3l, nullptr, H16, H16l,
        nullptr, nullptr, nullptr, nullptr,
        as3, ad3, sl, dl, nullptr, nullptr, nullptr, nullptr,
        nullptr, nullptr, nullptr, nullptr,
        nullptr, nullptr, nullptr, nullptr, nullptr, nullptr, nullptr, nullptr,
        NN, 256);
    gat_aggregate<<<aggBlocks, block, 0, stream>>>(cursor, bucket, sl, dl, H16, H16l, b3, Ph, Pl);

    // ---------------- MLP (Wm1 gemm + fused conflict-free Wm2 head) ----------
    gemm_mfma<false, true, true, false><<<mfmaGrid, block512, 0, stream>>>(
        nullptr, Ph, Pl, Bmh, Bml, bm1, nullptr, nullptr,
        Whh, Whl, bm2, out,
        nullptr, nullptr, nullptr, nullptr, nullptr, nullptr, nullptr, nullptr,
        nullptr, nullptr, nullptr, nullptr,
        nullptr, nullptr, nullptr, nullptr, nullptr, nullptr, nullptr, nullptr,
        NN, 256);
}

// Round 10
// 523.759 us; speedup vs baseline: 1.1256x; 1.0169x over previous
//
#include <hip/hip_runtime.h>

// GAT (3x GATConv + MLP head).
// R2: CSR gather. R4: split-f16 MFMA GEMM. R5: f16 messages + fused logits.
// R6: presplit A. R7: 4-stream gather. R9: async DMA staging, buckets.
// R10: hi/lo f16 message tables. R11/R12: aggregate structure, pinned at
//      3.9 TB/s random-gather floor (R13) -- FINAL.
// R14: nontemporal REGRESSED (revert R15). R16: gemm k-loop pipelining 568.3.
// R17: head fusion (conflicted) 589.5. R18: scatter-only fusion 539.6.
// R19: conflict-free head fusion (stride-264 spill, per-kq partials) +
//      W2..Wm2 conv into gemm1 grid: 532.6.
// R20: XCD-locality round. All compute kernels remap work via the m204
//      bijective chunked swizzle so XCD x owns node slice [x*NN/8, ...):
//      agg's Ph/Pl writes land in the same private L2 that gemm_{k+1}'s
//      A-staging reads (and gemm's H16 writes match agg's self reads).
//      Default bid%8 round-robin made every 51MB layer hand-off cross-XCD
//      -> HBM. Pure index remap, no numeric change. Also: cursor memset
//      folded into prep (one fewer launch).

constexpr int NN = 50000;
constexpr int NE = 800000;
constexpr int NN_PAD = 50176;   // DMA-gather padding for A tables
constexpr int CAP = 48;         // bucket capacity (Poisson(16) max ~40)
constexpr int GEMM_BLKS = (NN + 127) / 128;   // 391
constexpr int SCAT_BLKS = (NE + 511) / 512;   // 1563
constexpr int CONV_ELEMS = 241664 - 32768;    // W2..Wm2 conversions
constexpr int CONV_BLKS = CONV_ELEMS / 512;   // 408 (exact)

typedef _Float16 f16x8 __attribute__((ext_vector_type(8)));
typedef _Float16 f16x4 __attribute__((ext_vector_type(4)));
typedef float    f32x4 __attribute__((ext_vector_type(4)));

// m204 bijective chunked XCD swizzle: XCD x (= bid%8 under default
// round-robin dispatch) executes a contiguous chunk of the work range.
__device__ __forceinline__ int xcd_swz(int bid, int nwg)
{
    int q = nwg >> 3, r = nwg & 7;
    int xcd = bid & 7, rank = bid >> 3;
    return (xcd < r ? xcd * (q + 1) : r * (q + 1) + (xcd - r) * q) + rank;
}

// async global->LDS, 16B per lane; LDS dest = wave-uniform base + lane*16
__device__ __forceinline__ void cp16(void* lds, const void* g)
{
    __builtin_amdgcn_global_load_lds(
        (const __attribute__((address_space(1))) uint32_t*)g,
        (__attribute__((address_space(3))) uint32_t*)lds, 16, 0, 0);
}

// ---- weight pre-convert: B1 + cursor zeroing (memset folded in) ------------
__global__ __launch_bounds__(256)
void prep_kernel(const float* __restrict__ W1, _Float16* B1h, _Float16* B1l,
                 int* __restrict__ cursor)
{
    int bid = (int)blockIdx.x;
    if (bid >= 128) {                        // cursor zeroing blocks
        int i = (bid - 128) * 256 + (int)threadIdx.x;
        if (i < NN) cursor[i] = 0;
        return;
    }
    int idx = bid * 256 + (int)threadIdx.x;  // < 32768
    int k = idx >> 8, n = idx & 255;         // input layout [K=128][256]
    float v = W1[idx];
    _Float16 h = (_Float16)v;
    B1h[n * 128 + k] = h;
    B1l[n * 128 + k] = (_Float16)(v - (float)h);
}

// ---- split-f16 MFMA GEMM: [M,256] = A[M,K] @ B[K,256] ----------------------
// 512 thr (8 waves = 2 Mw x 4 Nw), tile M=128 x N=256, R16 pipeline.
// EXTRA: trailing blocks do edge-bucket scatter then W2..Wm2 conversion.
// HEADF: fused MLP head epilogue (out = relu(C+bias) @ Wm2 + bias2).
// R20: compute blocks take tile index via xcd_swz (XCD-contiguous rows).
template<bool FUSE, bool PRESPLIT, bool HEADF, bool EXTRA>
__global__ __launch_bounds__(512, 4)
void gemm_mfma(const float* __restrict__ A,
               const _Float16* Ah, const _Float16* Al,
               const _Float16* __restrict__ Bhi, const _Float16* __restrict__ Blo,
               const float* __restrict__ bias,
               _Float16* __restrict__ h16, _Float16* __restrict__ h16lo,
               const _Float16* __restrict__ Wh_hi, const _Float16* __restrict__ Wh_lo,
               const float* __restrict__ bias2, float* __restrict__ out,
               const float* __restrict__ a_src, const float* __restrict__ a_dst,
               float* __restrict__ sl, float* __restrict__ dl,
               const int* __restrict__ e_src, const int* __restrict__ e_dst,
               int* __restrict__ cursor, int* __restrict__ bucket,
               const float* __restrict__ W2c, const float* __restrict__ W3c,
               const float* __restrict__ Wm1c, const float* __restrict__ Wm2c,
               _Float16* B2hc, _Float16* B2lc, _Float16* B3hc, _Float16* B3lc,
               _Float16* Bmhc, _Float16* Bmlc, _Float16* Whhc, _Float16* Whlc,
               int M, int K)
{
    // 64 KB flat LDS: main loop uses sA dbuf (16KB x2) + sB (8KB x2 x2);
    // HEADF epilogue re-carves: hH[32][264] | hL[32][264] | redf[4][1632]f32.
    __shared__ __align__(16) _Float16 smem[32768];
    _Float16* sAhiP = smem;             // [2][128][32]: b*4096 + r*32
    _Float16* sAloP = smem + 8192;
    _Float16* sBhiP = smem + 16384;     // [256][32]: n*32
    _Float16* sBloP = smem + 24576;

    const int tid  = (int)threadIdx.x;

    if (EXTRA && (int)blockIdx.x >= GEMM_BLKS) {
        int xb = (int)blockIdx.x - GEMM_BLKS;
        if (xb < SCAT_BLKS) {
            int e = xb * 512 + tid;
            if (e < NE) {
                int d = e_dst[e];
                int pos = atomicAdd(&cursor[d], 1);
                if (pos < CAP) bucket[d * CAP + pos] = e_src[e];
            }
        } else {
            int cidx = (xb - SCAT_BLKS) * 512 + tid + 32768;
            const float* W; _Float16 *H, *Lo; int local;
            if (cidx < 98304)       { W = W2c;  H = B2hc; Lo = B2lc; local = cidx - 32768; }
            else if (cidx < 163840) { W = W3c;  H = B3hc; Lo = B3lc; local = cidx - 98304; }
            else if (cidx < 229376) { W = Wm1c; H = Bmhc; Lo = Bmlc; local = cidx - 163840; }
            else {
                int l = cidx - 229376; int n = l >> 8, k = l & 255;
                float v = (n < 40) ? Wm2c[k * 40 + n] : 0.f;
                _Float16 h = (_Float16)v;
                Whhc[l] = h; Whlc[l] = (_Float16)(v - (float)h);
                return;
            }
            int k = local >> 8, n = local & 255;     // [K=256][256] input
            float v = W[local];
            _Float16 h = (_Float16)v;
            H[n * 256 + k] = h;
            Lo[n * 256 + k] = (_Float16)(v - (float)h);
        }
        return;
    }

    const int wave = tid >> 6;
    const int mw   = wave >> 2;         // 0..1
    const int nw   = wave & 3;          // 0..3 == head
    const int lane = tid & 63;
    const int l15  = lane & 15;
    const int quad = lane >> 4;
    const int swz  = (l15 >> 1) & 3;    // read-side swizzle (row-dependent)
    const int wg   = xcd_swz((int)blockIdx.x, GEMM_BLKS);   // R20
    const int bm   = wg * 128;

    f32x4 acc[4][4];
    #pragma unroll
    for (int i = 0; i < 4; ++i)
        #pragma unroll
        for (int j = 0; j < 4; ++j)
            acc[i][j] = (f32x4){0.f, 0.f, 0.f, 0.f};

    // ---- staging helpers ----------------------------------------------------
    auto stageA_dma = [&](int b, int k0) {
        int rowA = wave * 16 + (lane >> 2);
        int c = (lane & 3) ^ ((rowA >> 1) & 3);
        cp16(sAhiP + b * 4096 + wave * 512, Ah + (size_t)(bm + rowA) * K + k0 + c * 8);
        cp16(sAloP + b * 4096 + wave * 512, Al + (size_t)(bm + rowA) * K + k0 + c * 8);
    };
    auto stageB = [&](int k0) {
        int pos = lane & 3;
        #pragma unroll
        for (int j = 0; j < 2; ++j) {
            int rowB = wave * 32 + j * 16 + (lane >> 2);
            int c = pos ^ ((rowB >> 1) & 3);
            cp16(sBhiP + (wave * 32 + j * 16) * 32, Bhi + (size_t)rowB * K + k0 + c * 8);
            cp16(sBloP + (wave * 32 + j * 16) * 32, Blo + (size_t)rowB * K + k0 + c * 8);
        }
    };
    const int ar = tid >> 2, ac = tid & 3;    // fp32-A path: 4 thr x 8 f16/row
    auto writeA_cvt = [&](int b, float4 v0, float4 v1) {
        float fv[8] = {v0.x, v0.y, v0.z, v0.w, v1.x, v1.y, v1.z, v1.w};
        f16x8 h8, l8;
        #pragma unroll
        for (int u = 0; u < 8; ++u) {
            _Float16 hh = (_Float16)fv[u];
            h8[u] = hh; l8[u] = (_Float16)(fv[u] - (float)hh);
        }
        int slot = (ac ^ ((ar >> 1) & 3)) * 8;
        *(f16x8*)(sAhiP + b * 4096 + ar * 32 + slot) = h8;
        *(f16x8*)(sAloP + b * 4096 + ar * 32 + slot) = l8;
    };
    auto loadA32 = [&](int k0, float4& v0, float4& v1) {
        int grow = bm + ar;
        v0 = make_float4(0.f, 0.f, 0.f, 0.f); v1 = v0;
        if (grow < M) {
            v0 = *(const float4*)(A + (size_t)grow * K + k0 + ac * 8);
            v1 = *(const float4*)(A + (size_t)grow * K + k0 + ac * 8 + 4);
        }
    };

    // ---- prologue: stage k=0 into buffer 0 ----------------------------------
    if (PRESPLIT) {
        stageA_dma(0, 0);
    } else {
        float4 v0, v1;
        loadA32(0, v0, v1);
        writeA_cvt(0, v0, v1);
    }
    stageB(0);
    __syncthreads();

    const int NT = K >> 5;
    for (int t = 0; t < NT; ++t) {
        const int cb = t & 1, nb = cb ^ 1;
        const bool pf = (t + 1 < NT);
        const int kn = (t + 1) << 5;

        float4 pv0, pv1;
        if (pf) {
            if (PRESPLIT) stageA_dma(nb, kn);
            else          loadA32(kn, pv0, pv1);
        }

        f16x8 bh[4], bl[4];
        #pragma unroll
        for (int nt = 0; nt < 4; ++nt) {
            int n = nw * 64 + nt * 16 + l15;
            bh[nt] = *(const f16x8*)(sBhiP + n * 32 + (quad ^ swz) * 8);
            bl[nt] = *(const f16x8*)(sBloP + n * 32 + (quad ^ swz) * 8);
        }
        #pragma unroll
        for (int mt = 0; mt < 4; ++mt) {
            int m = mw * 64 + mt * 16 + l15;
            f16x8 ah = *(const f16x8*)(sAhiP + cb * 4096 + m * 32 + (quad ^ swz) * 8);
            f16x8 al = *(const f16x8*)(sAloP + cb * 4096 + m * 32 + (quad ^ swz) * 8);
            #pragma unroll
            for (int nt = 0; nt < 4; ++nt) {
                acc[mt][nt] = __builtin_amdgcn_mfma_f32_16x16x32_f16(ah, bh[nt], acc[mt][nt], 0, 0, 0);
                acc[mt][nt] = __builtin_amdgcn_mfma_f32_16x16x32_f16(al, bh[nt], acc[mt][nt], 0, 0, 0);
                acc[mt][nt] = __builtin_amdgcn_mfma_f32_16x16x32_f16(ah, bl[nt], acc[mt][nt], 0, 0, 0);
            }
        }

        if (pf && !PRESPLIT) writeA_cvt(nb, pv0, pv1);

        if (pf) {
            __syncthreads();       // sB readers done; A(t+1) staging drained
            stageB(kn);            // B refill (L2-hot)
            __syncthreads();       // B visible for step t+1
        }
    }

    // ======================= fused MLP head epilogue =========================
    if (HEADF) {
        // re-carve LDS: hH/hL [32][264] (stride 264 f16 = 132 dw === 4 mod 32
        // -> b128 reads land uniform 8 dw/bank = minimum; spill writes ~2-way)
        _Float16* hH  = smem;                       // 8448 f16
        _Float16* hL  = smem + 8448;                // 8448 f16
        float*    redf = (float*)(smem + 16896);    // [4][1632] f32 (26KB)
        const int mh = wave & 1, kq = wave >> 1;
        __syncthreads();                            // all k-loop LDS reads done
        for (int mt = 0; mt < 4; ++mt) {
            // spill h = relu(C+bias) hi/lo for this chunk (rows mh*16+q*4+r)
            #pragma unroll
            for (int r = 0; r < 4; ++r) {
                int lrow = mw * 16 + quad * 4 + r;
                #pragma unroll
                for (int nt = 0; nt < 4; ++nt) {
                    int col = nw * 64 + nt * 16 + l15;
                    float v = fmaxf(acc[mt][nt][r] + bias[col], 0.f);
                    _Float16 hh = (_Float16)v;
                    hH[lrow * 264 + col] = hh;
                    hL[lrow * 264 + col] = (_Float16)(v - (float)hh);
                }
            }
            __syncthreads();
            // head MFMA: wave -> (m-half mh, k-quarter kq)
            f32x4 a3[3];
            #pragma unroll
            for (int nt = 0; nt < 3; ++nt) a3[nt] = (f32x4){0.f, 0.f, 0.f, 0.f};
            #pragma unroll
            for (int kc = 0; kc < 2; ++kc) {
                int k0 = kq * 64 + kc * 32;
                f16x8 ah = *(const f16x8*)&hH[(mh * 16 + l15) * 264 + k0 + quad * 8];
                f16x8 al = *(const f16x8*)&hL[(mh * 16 + l15) * 264 + k0 + quad * 8];
                #pragma unroll
                for (int nt = 0; nt < 3; ++nt) {
                    int n = nt * 16 + l15;
                    f16x8 bh = *(const f16x8*)(Wh_hi + n * 256 + k0 + quad * 8);
                    f16x8 bl = *(const f16x8*)(Wh_lo + n * 256 + k0 + quad * 8);
                    a3[nt] = __builtin_amdgcn_mfma_f32_16x16x32_f16(ah, bh, a3[nt], 0, 0, 0);
                    a3[nt] = __builtin_amdgcn_mfma_f32_16x16x32_f16(al, bh, a3[nt], 0, 0, 0);
                    a3[nt] = __builtin_amdgcn_mfma_f32_16x16x32_f16(ah, bl, a3[nt], 0, 0, 0);
                }
            }
            // store k-quarter partials (plain stores, per-kq slots)
            #pragma unroll
            for (int nt = 0; nt < 3; ++nt)
                #pragma unroll
                for (int rg = 0; rg < 4; ++rg)
                    redf[kq * 1632 + ((mh * 3 + nt) * 16 + l15) * 17 + quad * 4 + rg]
                        = a3[nt][rg];
            __syncthreads();
            if (kq == 0) {     // waves 0 (mh=0), 1 (mh=1) write the output
                #pragma unroll
                for (int rg = 0; rg < 4; ++rg) {
                    int grow = bm + mh * 64 + mt * 16 + quad * 4 + rg;
                    if (grow < M) {
                        #pragma unroll
                        for (int nt = 0; nt < 3; ++nt) {
                            int col = nt * 16 + l15;
                            if (col < 40) {
                                int ix = ((mh * 3 + nt) * 16 + l15) * 17 + quad * 4 + rg;
                                float s = ((redf[ix] + redf[1632 + ix])
                                         + redf[2 * 1632 + ix]) + redf[3 * 1632 + ix];
                                out[(size_t)grow * 40 + col] = s + bias2[col];
                            }
                        }
                    }
                }
            }
            __syncthreads();   // hH reuse next mt
        }
        return;
    }

    // ======================= normal epilogue =================================
    float aS[4], aD[4];
    if (FUSE) {
        #pragma unroll
        for (int nt = 0; nt < 4; ++nt) {
            aS[nt] = a_src[nw * 64 + nt * 16 + l15];
            aD[nt] = a_dst[nw * 64 + nt * 16 + l15];
        }
    }

    #pragma unroll
    for (int mt = 0; mt < 4; ++mt) {
        #pragma unroll
        for (int r = 0; r < 4; ++r) {
            int row = bm + mw * 64 + mt * 16 + quad * 4 + r;
            bool ok = (row < M);
            if (ok) {
                #pragma unroll
                for (int nt = 0; nt < 4; ++nt) {
                    int col = nw * 64 + nt * 16 + l15;
                    float c = acc[mt][nt][r];
                    _Float16 hh = (_Float16)c;
                    h16[(size_t)row * 256 + col] = hh;
                    h16lo[(size_t)row * 256 + col] = (_Float16)(c - (float)hh);
                }
            }
            if (FUSE) {
                float vs = 0.f, vd = 0.f;
                #pragma unroll
                for (int nt = 0; nt < 4; ++nt) {
                    float c = acc[mt][nt][r];
                    vs = fmaf(c, aS[nt], vs);
                    vd = fmaf(c, aD[nt], vd);
                }
                #pragma unroll
                for (int off = 8; off >= 1; off >>= 1) {
                    vs += __shfl_xor(vs, off, 64);
                    vd += __shfl_xor(vd, off, 64);
                }
                if (l15 == 0 && ok) {
                    sl[row * 4 + nw] = vs;
                    dl[row * 4 + nw] = vd;
                }
            }
        }
    }
}

__device__ __forceinline__ float leaky02(float a) {
    return (a >= 0.f) ? a : 0.2f * a;
}

// ---- fused softmax + aggregation: one wave per destination node ------------
// R12 structure (best measured). R20: node index via xcd_swz so XCD x owns
// the contiguous node slice it wrote in the producing gemm.
__global__ __launch_bounds__(256)
void gat_aggregate(const int* __restrict__ cursor, const int* __restrict__ bucket,
                   const float* __restrict__ sl, const float* __restrict__ dl,
                   const _Float16* __restrict__ h16, const _Float16* __restrict__ h16lo,
                   const float* __restrict__ bias,
                   _Float16* __restrict__ Ph, _Float16* __restrict__ Pl)
{
    __shared__ __align__(16) float sE[4][CAP][4];   // [wave][slot][head]
    __shared__ __align__(16) int   sIdx[4][CAP];    // [wave][slot]

    const int wv = (int)threadIdx.x >> 6;
    const int wg = xcd_swz((int)blockIdx.x, (int)gridDim.x);   // R20
    const int n = wg * 4 + wv;
    if (n >= NN) return;
    const int lane = (int)threadIdx.x & 63;
    const int head = lane >> 4;
    const int cnt = min(cursor[n], CAP);

    // ---- pass 1: one neighbor per lane -------------------------------------
    if (lane < cnt) {
        int s = bucket[(size_t)n * CAP + lane];
        sIdx[wv][lane] = s;
        float4 s4 = *(const float4*)(sl + s * 4);
        float4 d4 = *(const float4*)(dl + n * 4);
        float4 e4;
        e4.x = __expf(leaky02(s4.x + d4.x));
        e4.y = __expf(leaky02(s4.y + d4.y));
        e4.z = __expf(leaky02(s4.z + d4.z));
        e4.w = __expf(leaky02(s4.w + d4.w));
        *(float4*)&sE[wv][lane][0] = e4;
    }

    // ---- self-loop (stream 0): exact row = hi + lo -------------------------
    const float dlh = dl[n * 4 + head];
    float exs = __expf(leaky02(sl[n * 4 + head] + dlh));
    f16x4 shi = *(const f16x4*)(h16   + (size_t)n * 256 + lane * 4);
    f16x4 slo = *(const f16x4*)(h16lo + (size_t)n * 256 + lane * 4);
    float4 a0; float d0 = exs;
    a0.x = exs * ((float)shi[0] + (float)slo[0]);
    a0.y = exs * ((float)shi[1] + (float)slo[1]);
    a0.z = exs * ((float)shi[2] + (float)slo[2]);
    a0.w = exs * ((float)shi[3] + (float)slo[3]);
    float4 a1 = {0,0,0,0}, a2 = {0,0,0,0}, a3 = {0,0,0,0};
    float d1 = 0.f, d2 = 0.f, d3 = 0.f;

    const int vo = lane * 4;               // per-lane channel offset (f16 elems)
    int i = 0;
    for (; i + 3 < cnt; i += 4) {
        int s0 = __builtin_amdgcn_readfirstlane(sIdx[wv][i]);
        int s1 = __builtin_amdgcn_readfirstlane(sIdx[wv][i + 1]);
        int s2 = __builtin_amdgcn_readfirstlane(sIdx[wv][i + 2]);
        int s3 = __builtin_amdgcn_readfirstlane(sIdx[wv][i + 3]);
        float e0 = sE[wv][i][head];
        float e1 = sE[wv][i + 1][head];
        float e2 = sE[wv][i + 2][head];
        float e3 = sE[wv][i + 3][head];
        f16x4 h0 = *(const f16x4*)(h16 + ((size_t)(uint32_t)s0 << 8) + vo);
        f16x4 h1 = *(const f16x4*)(h16 + ((size_t)(uint32_t)s1 << 8) + vo);
        f16x4 h2 = *(const f16x4*)(h16 + ((size_t)(uint32_t)s2 << 8) + vo);
        f16x4 h3 = *(const f16x4*)(h16 + ((size_t)(uint32_t)s3 << 8) + vo);
        a0.x = fmaf(e0, (float)h0[0], a0.x); a0.y = fmaf(e0, (float)h0[1], a0.y);
        a0.z = fmaf(e0, (float)h0[2], a0.z); a0.w = fmaf(e0, (float)h0[3], a0.w);
        d0 += e0;
        a1.x = fmaf(e1, (float)h1[0], a1.x); a1.y = fmaf(e1, (float)h1[1], a1.y);
        a1.z = fmaf(e1, (float)h1[2], a1.z); a1.w = fmaf(e1, (float)h1[3], a1.w);
        d1 += e1;
        a2.x = fmaf(e2, (float)h2[0], a2.x); a2.y = fmaf(e2, (float)h2[1], a2.y);
        a2.z = fmaf(e2, (float)h2[2], a2.z); a2.w = fmaf(e2, (float)h2[3], a2.w);
        d2 += e2;
        a3.x = fmaf(e3, (float)h3[0], a3.x); a3.y = fmaf(e3, (float)h3[1], a3.y);
        a3.z = fmaf(e3, (float)h3[2], a3.z); a3.w = fmaf(e3, (float)h3[3], a3.w);
        d3 += e3;
    }
    for (; i < cnt; ++i) {
        int s0 = __builtin_amdgcn_readfirstlane(sIdx[wv][i]);
        float e0 = sE[wv][i][head];
        f16x4 h0 = *(const f16x4*)(h16 + ((size_t)(uint32_t)s0 << 8) + vo);
        a0.x = fmaf(e0, (float)h0[0], a0.x); a0.y = fmaf(e0, (float)h0[1], a0.y);
        a0.z = fmaf(e0, (float)h0[2], a0.z); a0.w = fmaf(e0, (float)h0[3], a0.w);
        d0 += e0;
    }
    float4 acc;
    acc.x = (a0.x + a1.x) + (a2.x + a3.x);
    acc.y = (a0.y + a1.y) + (a2.y + a3.y);
    acc.z = (a0.z + a1.z) + (a2.z + a3.z);
    acc.w = (a0.w + a1.w) + (a2.w + a3.w);
    float denom = (d0 + d1) + (d2 + d3);

    float inv = 1.f / denom;
    float4 bv = *(const float4*)(bias + lane * 4);
    float rv[4];
    rv[0] = fmaxf(bv.x + acc.x * inv, 0.f);
    rv[1] = fmaxf(bv.y + acc.y * inv, 0.f);
    rv[2] = fmaxf(bv.z + acc.z * inv, 0.f);
    rv[3] = fmaxf(bv.w + acc.w * inv, 0.f);
    f16x4 h, l;
    #pragma unroll
    for (int u = 0; u < 4; ++u) {
        _Float16 hh = (_Float16)rv[u];
        h[u] = hh; l[u] = (_Float16)(rv[u] - (float)hh);
    }
    *(f16x4*)(Ph + (size_t)n * 256 + vo) = h;
    *(f16x4*)(Pl + (size_t)n * 256 + vo) = l;
}

extern "C" void kernel_launch(void* const* d_in, const int* in_sizes, int n_in,
                              void* d_out, int out_size, void* d_ws, size_t ws_size,
                              hipStream_t stream)
{
    const float* x   = (const float*)d_in[0];
    const int*   ei  = (const int*)d_in[1];
    const int* src = ei;
    const int* dst = ei + NE;
    const float* W1  = (const float*)d_in[2];
    const float* as1 = (const float*)d_in[3];
    const float* ad1 = (const float*)d_in[4];
    const float* b1  = (const float*)d_in[5];
    const float* W2  = (const float*)d_in[6];
    const float* as2 = (const float*)d_in[7];
    const float* ad2 = (const float*)d_in[8];
    const float* b2  = (const float*)d_in[9];
    const float* W3  = (const float*)d_in[10];
    const float* as3 = (const float*)d_in[11];
    const float* ad3 = (const float*)d_in[12];
    const float* b3  = (const float*)d_in[13];
    const float* Wm1 = (const float*)d_in[14];
    const float* bm1 = (const float*)d_in[15];
    const float* Wm2 = (const float*)d_in[16];
    const float* bm2 = (const float*)d_in[17];
    float* out = (float*)d_out;

    float* ws  = (float*)d_ws;
    float* sl  = ws;                          // [NN,4]
    float* dl  = sl + NN * 4;
    int* cursor = (int*)(dl + NN * 4);        // [NN]
    int* bucket = cursor + NN;                // [NN*CAP]
    uintptr_t fb = (uintptr_t)(bucket + (size_t)NN * CAP);
    fb = (fb + 15) & ~(uintptr_t)15;
    _Float16* wb = (_Float16*)fb;
    _Float16* B1h = wb;                 _Float16* B1l = B1h + 256 * 128;
    _Float16* B2h = B1l + 256 * 128;    _Float16* B2l = B2h + 256 * 256;
    _Float16* B3h = B2l + 256 * 256;    _Float16* B3l = B3h + 256 * 256;
    _Float16* Bmh = B3l + 256 * 256;    _Float16* Bml = Bmh + 256 * 256;
    _Float16* Whh = Bml + 256 * 256;    _Float16* Whl = Whh + 48 * 256;
    _Float16* H16  = Whl + 48 * 256;                    // [NN,256] msg hi
    _Float16* H16l = H16 + (size_t)NN * 256;            // [NN,256] msg lo
    _Float16* Ph  = H16l + (size_t)NN * 256;            // [NN_PAD,256] A hi
    _Float16* Pl  = Ph   + (size_t)NN_PAD * 256;        // [NN_PAD,256] A lo

    const dim3 block(256);
    const dim3 block512(512);
    const dim3 g1Grid(GEMM_BLKS + SCAT_BLKS + CONV_BLKS); // gemm1+scatter+conv
    const dim3 mfmaGrid(GEMM_BLKS);
    const int aggBlocks = (NN + 3) / 4;       // 12500: 1 node/wave, 4 waves
    const int prepBlocks = 128 + (NN + 255) / 256;   // B1 conv + cursor zero

    // ---------------- B1 pre-convert + cursor zero (one launch) -------------
    prep_kernel<<<prepBlocks, block, 0, stream>>>(W1, B1h, B1l, cursor);

    // ------ Layer 1 (A = x fp32, K=128) + fused scatter + W2..Wm2 conv ------
    gemm_mfma<true, false, false, true><<<g1Grid, block512, 0, stream>>>(
        x, nullptr, nullptr, B1h, B1l, nullptr, H16, H16l,
        nullptr, nullptr, nullptr, nullptr,
        as1, ad1, sl, dl, src, dst, cursor, bucket,
        W2, W3, Wm1, Wm2, B2h, B2l, B3h, B3l, Bmh, Bml, Whh, Whl, NN, 128);
    gat_aggregate<<<aggBlocks, block, 0, stream>>>(cursor, bucket, sl, dl, H16, H16l, b1, Ph, Pl);

    // ---------------- Layer 2 (A presplit) ----------------------------------
    gemm_mfma<true, true, false, false><<<mfmaGrid, block512, 0, stream>>>(
        nullptr, Ph, Pl, B2h, B2l, nullptr, H16, H16l,
        nullptr, nullptr, nullptr, nullptr,
        as2, ad2, sl, dl, nullptr, nullptr, nullptr, nullptr,
        nullptr, nullptr, nullptr, nullptr,
        nullptr, nullptr, nullptr, nullptr, nullptr, nullptr, nullptr, nullptr,
        NN, 256);
    gat_aggregate<<<aggBlocks, block, 0, stream>>>(cursor, bucket, sl, dl, H16, H16l, b2, Ph, Pl);

    // ---------------- Layer 3 -----------------------------------------------
    gemm_mfma<true, true, false, false><<<mfmaGrid, block512, 0, stream>>>(
        nullptr, Ph, Pl, B3h, B3l, nullptr, H16, H16l,
        nullptr, nullptr, nullptr, nullptr,
        as3, ad3, sl, dl, nullptr, nullptr, nullptr, nullptr,
        nullptr, nullptr, nullptr, nullptr,
        nullptr, nullptr, nullptr, nullptr, nullptr, nullptr, nullptr, nullptr,
        NN, 256);
    gat_aggregate<<<aggBlocks, block, 0, stream>>>(cursor, bucket, sl, dl, H16, H16l, b3, Ph, Pl);

    // ---------------- MLP (Wm1 gemm + fused conflict-free Wm2 head) ----------
    gemm_mfma<false, true, true, false><<<mfmaGrid, block512, 0, stream>>>(
        nullptr, Ph, Pl, Bmh, Bml, bm1, nullptr, nullptr,
        Whh, Whl, bm2, out,
        nullptr, nullptr, nullptr, nullptr, nullptr, nullptr, nullptr, nullptr,
        nullptr, nullptr, nullptr, nullptr,
        nullptr, nullptr, nullptr, nullptr, nullptr, nullptr, nullptr, nullptr,
        NN, 256);
}